// Round 13
// baseline (1620.601 us; speedup 1.0000x reference)
//
#include <hip/hip_runtime.h>
#include <stdint.h>

#define DEV __device__ __forceinline__

typedef __attribute__((ext_vector_type(8))) short bf16x8;
typedef __attribute__((ext_vector_type(8))) unsigned short u16x8;
typedef __attribute__((ext_vector_type(4))) float f32x4;

// RNE-round f to bf16 (top 16 bits), plus the rounded-away fp32 remainder.
DEV unsigned short rne1(float f, float& rem) {
  uint32_t u = __float_as_uint(f);
  uint32_t t = (u + 0x7fffu + ((u >> 16) & 1u)) & 0xffff0000u;
  rem = f - __uint_as_float(t);
  return (unsigned short)(t >> 16);
}
DEV void split3(float f, unsigned short& a0, unsigned short& a1, unsigned short& a2) {
  float r1, r2;
  a0 = rne1(f, r1);
  a1 = rne1(r1, r2);
  uint32_t u = __float_as_uint(r2);
  a2 = (unsigned short)((u + 0x7fffu + ((u >> 16) & 1u)) >> 16);
}
DEV void split3_4(float4 v, ushort4& h0, ushort4& h1, ushort4& h2) {
  split3(v.x, h0.x, h1.x, h2.x);
  split3(v.y, h0.y, h1.y, h2.y);
  split3(v.z, h0.z, h1.z, h2.z);
  split3(v.w, h0.w, h1.w, h2.w);
}

// ================= conv0: normalize + 3x3 s1 p1 + relu =================
__global__ __launch_bounds__(256) void k_conv0(
    const float* __restrict__ x, const float* __restrict__ W,
    const float* __restrict__ b, float* __restrict__ y0, int base)
{
  __shared__ float sIn[3][34][34];
  const int t = threadIdx.x;
  const long img = base + blockIdx.x;
  const float mean[3] = {0.4914f, 0.4822f, 0.4465f};
  const float stdv[3] = {0.2023f, 0.1994f, 0.201f};
  for (int i = t; i < 3 * 34 * 34; i += 256) {
    int c = i / 1156, r = i % 1156, yy = r / 34 - 1, xx = r % 34 - 1;
    float v = 0.f;
    if ((unsigned)yy < 32u && (unsigned)xx < 32u)
      v = (x[((img * 3 + c) * 32 + yy) * 32 + xx] - mean[c]) / stdv[c];
    (&sIn[0][0][0])[i] = v;
  }
  __syncthreads();
  for (int p = t; p < 1024; p += 256) {
    const int py = p >> 5, px = p & 31;
    float in[27];
#pragma unroll
    for (int c = 0; c < 3; c++)
#pragma unroll
      for (int ky = 0; ky < 3; ky++)
#pragma unroll
        for (int kx = 0; kx < 3; kx++)
          in[c * 9 + ky * 3 + kx] = sIn[c][py + ky][px + kx];
#pragma unroll 4
    for (int oc = 0; oc < 32; oc++) {
      float acc = b[oc];
      const float* wp = W + oc * 27;
#pragma unroll
      for (int k = 0; k < 27; k++) acc += in[k] * wp[k];
      y0[(((long)blockIdx.x * 32 + oc) * 32 + py) * 32 + px] = fmaxf(acc, 0.f);
    }
  }
}

// ===== conv2 as MFMA split-3 implicit GEMM (R12-proven) =================
__global__ __launch_bounds__(256, 2) void k_conv2m(
    const float* __restrict__ y0, const float* __restrict__ W2,
    const float* __restrict__ bb, float* __restrict__ y2)
{
  __shared__ __align__(16) unsigned short sB[3][256][40];   // 61.4 KB
  const int t = threadIdx.x;
  const int lane = t & 63, wid = t >> 6;
  const int fr = lane & 15, kg = lane >> 4;
  const long img = blockIdx.x;
  const int py = t >> 4, px = t & 15;
  const float* yimg = y0 + img * (32 * 1024);

  f32x4 acc[2][4];
#pragma unroll
  for (int i = 0; i < 2; i++)
#pragma unroll
    for (int j = 0; j < 4; j++) acc[i][j] = (f32x4)0.f;

#pragma unroll 1
  for (int ks = 0; ks < 16; ks++) {
    __syncthreads();
#pragma unroll
    for (int icL = 0; icL < 2; icL++) {
      const int ic = ks * 2 + icL;
#pragma unroll
      for (int ky = 0; ky < 4; ky++) {
        const int iy = 2 * py + ky - 1;
        float v[4];
#pragma unroll
        for (int kx = 0; kx < 4; kx++) {
          const int ix = 2 * px + kx - 1;
          v[kx] = ((unsigned)iy < 32u && (unsigned)ix < 32u)
                    ? yimg[(ic * 32 + iy) * 32 + ix] : 0.f;
        }
        ushort4 h0, h1, h2;
        split3_4(make_float4(v[0], v[1], v[2], v[3]), h0, h1, h2);
        const int kloc = icL * 16 + ky * 4;
        *(ushort4*)&sB[0][t][kloc] = h0;
        *(ushort4*)&sB[1][t][kloc] = h1;
        *(ushort4*)&sB[2][t][kloc] = h2;
      }
    }
    __syncthreads();

    bf16x8 bfv[3][4];
#pragma unroll
    for (int s = 0; s < 3; s++)
#pragma unroll
      for (int nf = 0; nf < 4; nf++)
        bfv[s][nf] = *(const bf16x8*)&sB[s][wid * 64 + nf * 16 + fr][kg * 8];

#pragma unroll
    for (int mf = 0; mf < 2; mf++) {
      const float* wr = W2 + (long)(mf * 16 + fr) * 512 + ks * 32 + kg * 8;
      float4 w0 = *(const float4*)wr;
      float4 w1 = *(const float4*)(wr + 4);
      ushort4 p0, p1, p2, q0, q1, q2;
      split3_4(w0, p0, p1, p2);
      split3_4(w1, q0, q1, q2);
      bf16x8 a0, a1, a2;
      a0[0]=(short)p0.x; a0[1]=(short)p0.y; a0[2]=(short)p0.z; a0[3]=(short)p0.w;
      a0[4]=(short)q0.x; a0[5]=(short)q0.y; a0[6]=(short)q0.z; a0[7]=(short)q0.w;
      a1[0]=(short)p1.x; a1[1]=(short)p1.y; a1[2]=(short)p1.z; a1[3]=(short)p1.w;
      a1[4]=(short)q1.x; a1[5]=(short)q1.y; a1[6]=(short)q1.z; a1[7]=(short)q1.w;
      a2[0]=(short)p2.x; a2[1]=(short)p2.y; a2[2]=(short)p2.z; a2[3]=(short)p2.w;
      a2[4]=(short)q2.x; a2[5]=(short)q2.y; a2[6]=(short)q2.z; a2[7]=(short)q2.w;
#pragma unroll
      for (int nf = 0; nf < 4; nf++) {
        f32x4 a = acc[mf][nf];
        a = __builtin_amdgcn_mfma_f32_16x16x32_bf16(a1, bfv[1][nf], a, 0, 0, 0);
        a = __builtin_amdgcn_mfma_f32_16x16x32_bf16(a0, bfv[2][nf], a, 0, 0, 0);
        a = __builtin_amdgcn_mfma_f32_16x16x32_bf16(a2, bfv[0][nf], a, 0, 0, 0);
        a = __builtin_amdgcn_mfma_f32_16x16x32_bf16(a1, bfv[0][nf], a, 0, 0, 0);
        a = __builtin_amdgcn_mfma_f32_16x16x32_bf16(a0, bfv[1][nf], a, 0, 0, 0);
        a = __builtin_amdgcn_mfma_f32_16x16x32_bf16(a0, bfv[0][nf], a, 0, 0, 0);
        acc[mf][nf] = a;
      }
    }
  }
#pragma unroll
  for (int mf = 0; mf < 2; mf++)
#pragma unroll
    for (int nf = 0; nf < 4; nf++) {
      const int pix = wid * 64 + nf * 16 + fr;
#pragma unroll
      for (int reg = 0; reg < 4; reg++) {
        const int oc = mf * 16 + kg * 4 + reg;
        y2[(img * 32 + oc) * 256 + pix] = fmaxf(acc[mf][nf][reg] + bb[oc], 0.f);
      }
    }
}

// ===== pre-split conv4 weights: W4 [64][32][3][3] -> [plane][tap][oc][ic] =
__global__ __launch_bounds__(256) void k_splitW4(
    const float* __restrict__ W, unsigned short* __restrict__ Wsp)
{
  const int i = blockIdx.x * 256 + threadIdx.x;   // 64*288 = 18432
  if (i >= 64 * 288) return;
  const int o = i / 288, r = i % 288, ic = r / 9, tap = r % 9;
  unsigned short a0, a1, a2;
  split3(W[i], a0, a1, a2);
  const int base = (tap * 64 + o) * 32 + ic;
  Wsp[base] = a0;
  Wsp[18432 + base] = a1;
  Wsp[36864 + base] = a2;
}

// ===== conv4 as MFMA split-3 implicit GEMM (R10-proven) =================
__global__ __launch_bounds__(256, 2) void k_conv4m(
    const float* __restrict__ y2, const unsigned short* __restrict__ Wsp,
    const float* __restrict__ bb, float* __restrict__ y4)
{
  __shared__ __align__(16) unsigned short sX[3][324][40];   // 77.8 KB
  const int t = threadIdx.x;
  const int lane = t & 63, wid = t >> 6;
  const int fr = lane & 15, kg = lane >> 4;
  const long img = blockIdx.x;
  const float* yimg = y2 + img * (32 * 256);

  for (int i = t; i < 324 * 32; i += 256) {
    const int ic = i / 324, pos = i % 324;
    const int iy = pos / 18, ix = pos % 18;
    float v = 0.f;
    if ((unsigned)(iy - 1) < 16u && (unsigned)(ix - 1) < 16u)
      v = yimg[(ic * 16 + iy - 1) * 16 + ix - 1];
    unsigned short a0, a1, a2;
    split3(v, a0, a1, a2);
    sX[0][pos][ic] = a0;
    sX[1][pos][ic] = a1;
    sX[2][pos][ic] = a2;
  }
  __syncthreads();

  f32x4 acc[4][4];
#pragma unroll
  for (int i = 0; i < 4; i++)
#pragma unroll
    for (int j = 0; j < 4; j++) acc[i][j] = (f32x4)0.f;

  const int pyb = wid * 4;
#pragma unroll 1
  for (int tap = 0; tap < 9; tap++) {
    const int ky = tap / 3, kx = tap % 3;
    bf16x8 bfv[3][4];
#pragma unroll
    for (int s = 0; s < 3; s++)
#pragma unroll
      for (int nf = 0; nf < 4; nf++)
        bfv[s][nf] = *(const bf16x8*)&sX[s][(pyb + nf + ky) * 18 + fr + kx][kg * 8];
#pragma unroll
    for (int mf = 0; mf < 4; mf++) {
      const int wb = (tap * 64 + mf * 16 + fr) * 32 + kg * 8;
      bf16x8 a0 = *(const bf16x8*)&Wsp[wb];
      bf16x8 a1 = *(const bf16x8*)&Wsp[18432 + wb];
      bf16x8 a2 = *(const bf16x8*)&Wsp[36864 + wb];
#pragma unroll
      for (int nf = 0; nf < 4; nf++) {
        f32x4 a = acc[mf][nf];
        a = __builtin_amdgcn_mfma_f32_16x16x32_bf16(a1, bfv[1][nf], a, 0, 0, 0);
        a = __builtin_amdgcn_mfma_f32_16x16x32_bf16(a0, bfv[2][nf], a, 0, 0, 0);
        a = __builtin_amdgcn_mfma_f32_16x16x32_bf16(a2, bfv[0][nf], a, 0, 0, 0);
        a = __builtin_amdgcn_mfma_f32_16x16x32_bf16(a1, bfv[0][nf], a, 0, 0, 0);
        a = __builtin_amdgcn_mfma_f32_16x16x32_bf16(a0, bfv[1][nf], a, 0, 0, 0);
        a = __builtin_amdgcn_mfma_f32_16x16x32_bf16(a0, bfv[0][nf], a, 0, 0, 0);
        acc[mf][nf] = a;
      }
    }
  }
#pragma unroll
  for (int mf = 0; mf < 4; mf++)
#pragma unroll
    for (int nf = 0; nf < 4; nf++) {
      const int p2 = wid * 64 + nf * 16 + fr;
#pragma unroll
      for (int reg = 0; reg < 4; reg++) {
        const int oc = mf * 16 + kg * 4 + reg;
        y4[(img * 64 + oc) * 256 + p2] = fmaxf(acc[mf][nf][reg] + bb[oc], 0.f);
      }
    }
}

// ===== pre-split conv6 weights: W6 [256][1024] fp32 -> 3 bf16 planes ====
__global__ __launch_bounds__(256) void k_splitW(
    const float* __restrict__ W, unsigned short* __restrict__ Wsp)
{
  const int i = (blockIdx.x * 256 + threadIdx.x) * 4;   // 262144 total
  float4 v = *(const float4*)&W[i];
  ushort4 h0, h1, h2; split3_4(v, h0, h1, h2);
  *(ushort4*)&Wsp[i]          = h0;
  *(ushort4*)&Wsp[262144 + i] = h1;
  *(ushort4*)&Wsp[524288 + i] = h2;
}

// ===== conv6 as MFMA split-3 implicit GEMM (R8-proven) ==================
__global__ __launch_bounds__(256) void k_conv6m(
    const float* __restrict__ y4, const unsigned short* __restrict__ Wsp,
    const float* __restrict__ bb, float* __restrict__ c6)
{
  __shared__ __align__(16) unsigned short sB[3][64][56];
  const int t = threadIdx.x;
  const int lane = t & 63, wid = t >> 6;
  const int fr = lane & 15, kg = lane >> 4;
  const long img = blockIdx.x;
  const int pix = t >> 2, q = t & 3;
  const int spy = pix >> 3, spx = pix & 7;
  const int icL = q >> 1, kyB = (q & 1) * 2;
  const float* yimg = y4 + img * (64 * 256);

  f32x4 acc[4][4];
#pragma unroll
  for (int i = 0; i < 4; i++)
#pragma unroll
    for (int j = 0; j < 4; j++) acc[i][j] = (f32x4)0.f;

#pragma unroll 1
  for (int ks = 0; ks < 32; ks++) {
    const int ic = ks * 2 + icL;
    float v[8];
#pragma unroll
    for (int j = 0; j < 8; j++) {
      const int ky = kyB + (j >> 2), kx = j & 3;
      const int iy = 2 * spy + ky - 1, ix = 2 * spx + kx - 1;
      v[j] = ((unsigned)iy < 16u && (unsigned)ix < 16u)
               ? yimg[(ic * 16 + iy) * 16 + ix] : 0.f;
    }
    u16x8 h0, h1, h2;
#pragma unroll
    for (int j = 0; j < 8; j++) {
      unsigned short a0, a1, a2;
      split3(v[j], a0, a1, a2);
      h0[j] = a0; h1[j] = a1; h2[j] = a2;
    }
    __syncthreads();
    *(u16x8*)&sB[0][pix][q * 8] = h0;
    *(u16x8*)&sB[1][pix][q * 8] = h1;
    *(u16x8*)&sB[2][pix][q * 8] = h2;
    __syncthreads();

    bf16x8 bfv[3][4];
#pragma unroll
    for (int s = 0; s < 3; s++)
#pragma unroll
      for (int nf = 0; nf < 4; nf++)
        bfv[s][nf] = *(const bf16x8*)&sB[s][nf * 16 + fr][kg * 8];

    const int kbase = ks * 32 + kg * 8;
#pragma unroll
    for (int mf = 0; mf < 4; mf++) {
      const int oc = wid * 64 + mf * 16 + fr;
      bf16x8 a0 = *(const bf16x8*)&Wsp[(long)oc * 1024 + kbase];
      bf16x8 a1 = *(const bf16x8*)&Wsp[(long)(256 + oc) * 1024 + kbase];
      bf16x8 a2 = *(const bf16x8*)&Wsp[(long)(512 + oc) * 1024 + kbase];
#pragma unroll
      for (int nf = 0; nf < 4; nf++) {
        f32x4 a = acc[mf][nf];
        a = __builtin_amdgcn_mfma_f32_16x16x32_bf16(a1, bfv[1][nf], a, 0, 0, 0);
        a = __builtin_amdgcn_mfma_f32_16x16x32_bf16(a0, bfv[2][nf], a, 0, 0, 0);
        a = __builtin_amdgcn_mfma_f32_16x16x32_bf16(a2, bfv[0][nf], a, 0, 0, 0);
        a = __builtin_amdgcn_mfma_f32_16x16x32_bf16(a1, bfv[0][nf], a, 0, 0, 0);
        a = __builtin_amdgcn_mfma_f32_16x16x32_bf16(a0, bfv[1][nf], a, 0, 0, 0);
        a = __builtin_amdgcn_mfma_f32_16x16x32_bf16(a0, bfv[0][nf], a, 0, 0, 0);
        acc[mf][nf] = a;
      }
    }
  }
#pragma unroll
  for (int mf = 0; mf < 4; mf++)
#pragma unroll
    for (int nf = 0; nf < 4; nf++) {
      const int ocb = wid * 64 + mf * 16 + kg * 4;
      const int p2 = nf * 16 + fr;
#pragma unroll
      for (int reg = 0; reg < 4; reg++) {
        const int oc = ocb + reg;
        c6[(img * 256 + oc) * 64 + p2] = acc[mf][nf][reg] + bb[oc];
      }
    }
}

// ====== fp32 score GEMM v3: (TM*8) x 128 tile, 8x8/thread ===============
// LDS-balance fix: 1 B/FMA (vs 2 for 4x4). B stored as lo/hi float4 planes
// so the 16 tx-lanes read 256 contiguous bytes (conflict-free); A read is
// 4-address broadcast. Per-output-element k-order IDENTICAL to the R10
// kernel (16-k tiles, sequential inner FMA, two-level acc) -> scores
// bit-identical. Fully static indexing (no R11-style spill structure).
template<int TM, int DO_ABS, int SPLITK>   // block = TM*16 threads
__global__ __launch_bounds__(TM * 16, 2) void k_sgemm8(
    const float* __restrict__ A, const float* __restrict__ Bm,
    const float* __restrict__ bias, float* __restrict__ C,
    int M, int N, int K)
{
  constexpr int BM = TM * 8;
  __shared__ float As[16][BM + 4];
  __shared__ float4 Blo[16][17], Bhi[16][17];
  const int t = threadIdx.x;
  const int tx = t & 15, ty = t >> 4;
  const int n0 = blockIdx.x * 128, m0 = blockIdx.y * BM;
  const int Kc = K / SPLITK, k0 = blockIdx.z * Kc;
  float acc[8][8] = {{0.f}};

  for (int kt = 0; kt < Kc; kt += 16) {
    __syncthreads();
    {
      const int kc = t & 15, r0 = t >> 4;
#pragma unroll
      for (int i = 0; i < 8; i++)
        As[kc][r0 + TM * i] = A[(long)(m0 + r0 + TM * i) * K + k0 + kt + kc];
      const int nc4 = t & 31, kr = t >> 5;
#pragma unroll
      for (int i = 0; i < 512 / (TM * 16); i++) {
        const int k = kr + (TM / 2) * i;
        float4 v = *(const float4*)&Bm[(long)(k0 + kt + k) * N + n0 + nc4 * 4];
        if (nc4 & 1) Bhi[k][nc4 >> 1] = v; else Blo[k][nc4 >> 1] = v;
      }
    }
    __syncthreads();
    float part[8][8] = {{0.f}};
#pragma unroll
    for (int k = 0; k < 16; k++) {
      float4 a0 = *(const float4*)&As[k][ty * 8];
      float4 a1 = *(const float4*)&As[k][ty * 8 + 4];
      float4 b0 = Blo[k][tx];
      float4 b1 = Bhi[k][tx];
      const float a[8] = {a0.x, a0.y, a0.z, a0.w, a1.x, a1.y, a1.z, a1.w};
      const float b[8] = {b0.x, b0.y, b0.z, b0.w, b1.x, b1.y, b1.z, b1.w};
#pragma unroll
      for (int i = 0; i < 8; i++)
#pragma unroll
        for (int j = 0; j < 8; j++)
          part[i][j] += a[i] * b[j];
    }
#pragma unroll
    for (int i = 0; i < 8; i++)
#pragma unroll
      for (int j = 0; j < 8; j++)
        acc[i][j] += part[i][j];
  }

  float* dst = (SPLITK == 1) ? C : C + (long)blockIdx.z * M * N;
#pragma unroll
  for (int i = 0; i < 8; i++) {
    const long m = m0 + ty * 8 + i;
    float v0[4], v1[4];
#pragma unroll
    for (int j = 0; j < 4; j++) {
      float u = acc[i][j], w = acc[i][j + 4];
      if (SPLITK == 1) {
        u += bias[n0 + tx * 8 + j];
        w += bias[n0 + tx * 8 + 4 + j];
        if (DO_ABS) { u = fabsf(u); w = fabsf(w); }
      }
      v0[j] = u; v1[j] = w;
    }
    *(float4*)(dst + m * N + n0 + tx * 8) = make_float4(v0[0], v0[1], v0[2], v0[3]);
    *(float4*)(dst + m * N + n0 + tx * 8 + 4) = make_float4(v1[0], v1[1], v1[2], v1[3]);
  }
}

// ====== fp32 score GEMM (R10-proven 64x64; scores11 only) ===============
template<int B_NK, int DO_ABS, int SPLITK>
__global__ __launch_bounds__(256, 4) void k_sgemm(
    const float* __restrict__ A, const float* __restrict__ Bm,
    const float* __restrict__ bias, float* __restrict__ C,
    int M, int N, int K)
{
  __shared__ float As[16][68];
  __shared__ float Bs[16][68];
  const int t = threadIdx.x;
  const int tx = t & 15, ty = t >> 4;
  const int n0 = blockIdx.x * 64, m0 = blockIdx.y * 64;
  const int Kc = K / SPLITK;
  const int k0 = blockIdx.z * Kc;
  float acc[4][4] = {{0.f}};
  for (int kt = 0; kt < Kc; kt += 16) {
    __syncthreads();
    {
      const int kc = t & 15, r0 = t >> 4;
#pragma unroll
      for (int i = 0; i < 4; i++)
        As[kc][r0 + 16 * i] = A[(long)(m0 + r0 + 16 * i) * K + k0 + kt + kc];
      if (B_NK) {
#pragma unroll
        for (int i = 0; i < 4; i++)
          Bs[kc][r0 + 16 * i] = Bm[(long)(n0 + r0 + 16 * i) * K + k0 + kt + kc];
      } else {
        const int nc = t & 63, kr0 = t >> 6;
#pragma unroll
        for (int i = 0; i < 4; i++)
          Bs[kr0 + 4 * i][nc] = Bm[(long)(k0 + kt + kr0 + 4 * i) * N + n0 + nc];
      }
    }
    __syncthreads();
    float part[4][4] = {{0.f}};
#pragma unroll
    for (int k = 0; k < 16; k++) {
      float4 av = *(const float4*)&As[k][ty * 4];
      float4 bv = *(const float4*)&Bs[k][tx * 4];
      const float a[4] = {av.x, av.y, av.z, av.w};
      const float bb[4] = {bv.x, bv.y, bv.z, bv.w};
#pragma unroll
      for (int i = 0; i < 4; i++)
#pragma unroll
        for (int j = 0; j < 4; j++)
          part[i][j] += a[i] * bb[j];
    }
#pragma unroll
    for (int i = 0; i < 4; i++)
#pragma unroll
      for (int j = 0; j < 4; j++)
        acc[i][j] += part[i][j];
  }
#pragma unroll
  for (int i = 0; i < 4; i++) {
    const long m = m0 + ty * 4 + i;
    float vv[4];
#pragma unroll
    for (int j = 0; j < 4; j++) {
      float u = acc[i][j];
      if (SPLITK == 1) {
        u += bias[n0 + tx * 4 + j];
        if (DO_ABS) u = fabsf(u);
      }
      vv[j] = u;
    }
    float4 v; v.x = vv[0]; v.y = vv[1]; v.z = vv[2]; v.w = vv[3];
    float* dst = (SPLITK == 1) ? &C[m * N + n0 + tx * 4]
                               : &C[((long)blockIdx.z * M + m) * N + n0 + tx * 4];
    *(float4*)dst = v;
  }
}

// ===== MFMA split-3 GEMM (live-certified B_NK=1; lin paths only) ========
template<int B_NK, int DO_ABS, int SPLITK>
__global__ __launch_bounds__(256, 2) void k_mgemm(
    const float* __restrict__ A, const float* __restrict__ Bm,
    const float* __restrict__ bias, float* __restrict__ C,
    int M, int N, int K)
{
  __shared__ __align__(16) unsigned short sA[3][64][40];
  __shared__ __align__(16) unsigned short sB[3][128][40];
  const int t = threadIdx.x;
  const int n0 = blockIdx.x * 128, m0 = blockIdx.y * 64;
  const int Kc = K / SPLITK;
  const int k0 = blockIdx.z * Kc;
  const int lane = t & 63, wid = t >> 6;
  const int wm = wid >> 1, wn = wid & 1;
  const int fr = lane & 15, kg = lane >> 4;

  f32x4 acc[2][4];
#pragma unroll
  for (int i = 0; i < 2; i++)
#pragma unroll
    for (int j = 0; j < 4; j++) acc[i][j] = (f32x4)0.f;

  for (int kt = 0; kt < Kc; kt += 32) {
    __syncthreads();
    {
      const int kq = t & 7, r = t >> 3;
#pragma unroll
      for (int i = 0; i < 2; i++) {
        float4 v = *(const float4*)&A[(long)(m0 + r + 32 * i) * K + k0 + kt + kq * 4];
        ushort4 h0, h1, h2; split3_4(v, h0, h1, h2);
        *(ushort4*)&sA[0][r + 32 * i][kq * 4] = h0;
        *(ushort4*)&sA[1][r + 32 * i][kq * 4] = h1;
        *(ushort4*)&sA[2][r + 32 * i][kq * 4] = h2;
      }
    }
    if (B_NK) {
      const int kq = t & 7, r = t >> 3;
#pragma unroll
      for (int i = 0; i < 4; i++) {
        float4 v = *(const float4*)&Bm[(long)(n0 + r + 32 * i) * K + k0 + kt + kq * 4];
        ushort4 h0, h1, h2; split3_4(v, h0, h1, h2);
        *(ushort4*)&sB[0][r + 32 * i][kq * 4] = h0;
        *(ushort4*)&sB[1][r + 32 * i][kq * 4] = h1;
        *(ushort4*)&sB[2][r + 32 * i][kq * 4] = h2;
      }
    } else {
      const int nq = t & 31, kr = t >> 5;
#pragma unroll
      for (int i = 0; i < 4; i++) {
        const int k = kr + 8 * i;
        float4 v = *(const float4*)&Bm[(long)(k0 + kt + k) * N + n0 + nq * 4];
        ushort4 h0, h1, h2; split3_4(v, h0, h1, h2);
        sB[0][nq * 4 + 0][k] = h0.x; sB[1][nq * 4 + 0][k] = h1.x; sB[2][nq * 4 + 0][k] = h2.x;
        sB[0][nq * 4 + 1][k] = h0.y; sB[1][nq * 4 + 1][k] = h1.y; sB[2][nq * 4 + 1][k] = h2.y;
        sB[0][nq * 4 + 2][k] = h0.z; sB[1][nq * 4 + 2][k] = h1.z; sB[2][nq * 4 + 2][k] = h2.z;
        sB[0][nq * 4 + 3][k] = h0.w; sB[1][nq * 4 + 3][k] = h1.w; sB[2][nq * 4 + 3][k] = h2.w;
      }
    }
    __syncthreads();

    bf16x8 af[3][2], bfv[3][4];
#pragma unroll
    for (int s = 0; s < 3; s++)
#pragma unroll
      for (int mf = 0; mf < 2; mf++)
        af[s][mf] = *(const bf16x8*)&sA[s][wm * 32 + mf * 16 + fr][kg * 8];
#pragma unroll
    for (int s = 0; s < 3; s++)
#pragma unroll
      for (int nf = 0; nf < 4; nf++)
        bfv[s][nf] = *(const bf16x8*)&sB[s][wn * 64 + nf * 16 + fr][kg * 8];

#pragma unroll
    for (int mf = 0; mf < 2; mf++)
#pragma unroll
      for (int nf = 0; nf < 4; nf++) {
        f32x4 a = acc[mf][nf];
        a = __builtin_amdgcn_mfma_f32_16x16x32_bf16(af[1][mf], bfv[1][nf], a, 0, 0, 0);
        a = __builtin_amdgcn_mfma_f32_16x16x32_bf16(af[0][mf], bfv[2][nf], a, 0, 0, 0);
        a = __builtin_amdgcn_mfma_f32_16x16x32_bf16(af[2][mf], bfv[0][nf], a, 0, 0, 0);
        a = __builtin_amdgcn_mfma_f32_16x16x32_bf16(af[1][mf], bfv[0][nf], a, 0, 0, 0);
        a = __builtin_amdgcn_mfma_f32_16x16x32_bf16(af[0][mf], bfv[1][nf], a, 0, 0, 0);
        a = __builtin_amdgcn_mfma_f32_16x16x32_bf16(af[0][mf], bfv[0][nf], a, 0, 0, 0);
        acc[mf][nf] = a;
      }
  }

  float* dst = (SPLITK == 1) ? C : C + (long)blockIdx.z * M * N;
#pragma unroll
  for (int mf = 0; mf < 2; mf++)
#pragma unroll
    for (int nf = 0; nf < 4; nf++) {
      const int n = n0 + wn * 64 + nf * 16 + fr;
      const int mb = m0 + wm * 32 + mf * 16 + kg * 4;
#pragma unroll
      for (int reg = 0; reg < 4; reg++) {
        float u = acc[mf][nf][reg];
        if (SPLITK == 1) {
          u += bias[n];
          if (DO_ABS) u = fabsf(u);
        }
        dst[(long)(mb + reg) * N + n] = u;
      }
    }
}

// ================= split-K reduce for scores6 (16 partials) ==============
__global__ __launch_bounds__(256) void k_reduce6(
    const float* __restrict__ part, const float* __restrict__ br,
    float* __restrict__ s6, int rows)
{
  const int i = blockIdx.x * 256 + threadIdx.x;
  const int tot = rows * 256;
  if (i < tot) {
    float s = br[i & 255];
#pragma unroll
    for (int z = 0; z < 16; z++) s += part[z * tot + i];
    s6[i] = fabsf(s);
  }
}

// ================= split-K reduce for scores9 (2 partials, N=2048) =======
__global__ __launch_bounds__(256) void k_reduce9(
    const float* __restrict__ part, const float* __restrict__ br,
    float* __restrict__ s9)
{
  const int i = blockIdx.x * 256 + threadIdx.x;   // 1024*2048 total
  const int tot = 1024 * 2048;
  s9[i] = fabsf(part[i] + part[tot + i] + br[i & 2047]);
}

// ================= block helpers =================
DEV int blk_reduce(int v, volatile int* sW4) {
#pragma unroll
  for (int d = 32; d > 0; d >>= 1) v += __shfl_down(v, d);
  const int lane = threadIdx.x & 63, wid = threadIdx.x >> 6;
  if (lane == 0) sW4[wid] = v;
  __syncthreads();
  int tot = sW4[0] + sW4[1] + sW4[2] + sW4[3];
  __syncthreads();
  return tot;
}

DEV int blk_exscan(int v, volatile int* sW4) {
  const int lane = threadIdx.x & 63, wid = threadIdx.x >> 6;
  int inc = v;
#pragma unroll
  for (int d = 1; d < 64; d <<= 1) {
    int u = __shfl_up(inc, d);
    if (lane >= d) inc += u;
  }
  if (lane == 63) sW4[wid] = inc;
  __syncthreads();
  int off = 0;
#pragma unroll
  for (int w = 0; w < 3; w++)
    if (w < wid) off += sW4[w];
  __syncthreads();
  return off + inc - v;
}

// ================= top-k select + gather (+relu) =================
template<int N, int KEEP, int SPATIAL>
__global__ __launch_bounds__(256) void k_topk(
    const float* __restrict__ scores, const float* __restrict__ full,
    float* __restrict__ out)
{
  constexpr int E = N / 256;
  __shared__ int sW4[4];
  __shared__ int sSel[KEEP];
  const int t = threadIdx.x;
  const long row = blockIdx.x;
  uint32_t kk[E];
#pragma unroll
  for (int e = 0; e < E; e++) kk[e] = __float_as_uint(scores[row * N + t * E + e]);
  uint32_t prefix = 0u;
  for (int bit = 31; bit >= 0; bit--) {
    uint32_t cand = prefix | (1u << bit);
    int c = 0;
#pragma unroll
    for (int e = 0; e < E; e++) c += (kk[e] >= cand) ? 1 : 0;
    if (blk_reduce(c, sW4) >= KEEP) prefix = cand;
  }
  int myG = 0, myE = 0;
#pragma unroll
  for (int e = 0; e < E; e++) { myG += kk[e] > prefix; myE += kk[e] == prefix; }
  const int G = blk_reduce(myG, sW4);
  const int needEq = KEEP - G;
  const int prefE = blk_exscan(myE, sW4);
  const int keepcnt = myG + max(0, min(myE, needEq - prefE));
  int pos = blk_exscan(keepcnt, sW4);
  int eqSeen = prefE;
#pragma unroll
  for (int e = 0; e < E; e++) {
    const bool kp = (kk[e] > prefix) || ((kk[e] == prefix) && (eqSeen < needEq));
    if (kk[e] == prefix) eqSeen++;
    if (kp) sSel[pos++] = t * E + e;
  }
  __syncthreads();
  if (SPATIAL) {
    for (int i = t; i < KEEP * 64; i += 256)
      out[row * (KEEP * 64) + i] = fmaxf(full[(row * N + sSel[i >> 6]) * 64 + (i & 63)], 0.f);
  } else {
    for (int i = t; i < KEEP; i += 256)
      out[row * KEEP + i] = fmaxf(full[row * N + sSel[i]], 0.f);
  }
}

// ================= final: lin13 + scores13 + top-10-of-40 =================
__global__ __launch_bounds__(256) void k_final(
    const float* __restrict__ y11, const float* __restrict__ W13,
    const float* __restrict__ b13, const float* __restrict__ Wr13,
    const float* __restrict__ br13, float* __restrict__ outp)
{
  __shared__ float sX[512];
  __shared__ float sL[64];
  __shared__ float sS[64];
  const int t = threadIdx.x;
  const long row = blockIdx.x;
  for (int i = t; i < 512; i += 256) sX[i] = y11[row * 512 + i];
  __syncthreads();
  if (t < 40) {
    float acc = b13[t];
    const float4* w4 = (const float4*)(W13 + t * 512);
    for (int k = 0; k < 128; k++) {
      float4 w = w4[k];
      acc += sX[4 * k] * w.x + sX[4 * k + 1] * w.y + sX[4 * k + 2] * w.z + sX[4 * k + 3] * w.w;
    }
    sL[t] = acc;
  } else if (t >= 64 && t < 104) {
    const int n = t - 64;
    float acc = br13[n];
    for (int k = 0; k < 512; k++) acc += sX[k] * Wr13[k * 40 + n];
    sS[n] = fabsf(acc);
  }
  __syncthreads();
  if (t < 64) {
    const uint32_t key = (t < 40) ? __float_as_uint(sS[t]) : 0u;
    uint32_t prefix = 0u;
#pragma unroll
    for (int bit = 31; bit >= 0; bit--) {
      uint32_t cand = prefix | (1u << bit);
      unsigned long long m = __ballot(t < 40 && key >= cand);
      if (__popcll(m) >= 10) prefix = cand;
    }
    const int G = __popcll(__ballot(t < 40 && key > prefix));
    const int needEq = 10 - G;
    const unsigned long long me = __ballot(t < 40 && key == prefix);
    const unsigned long long lt = (t == 0) ? 0ull : (~0ull >> (64 - t));
    const int eqr = __popcll(me & lt);
    const bool kp = (t < 40) && ((key > prefix) || (key == prefix && eqr < needEq));
    const int pos = __popcll(__ballot(kp) & lt);
    if (kp) outp[row * 10 + pos] = sL[t];
  }
}

// ================= launch =================
extern "C" void kernel_launch(void* const* d_in, const int* in_sizes, int n_in,
                              void* d_out, int out_size, void* d_ws, size_t ws_size,
                              hipStream_t stream)
{
  const float* x    = (const float*)d_in[0];
  const float* W0   = (const float*)d_in[1];
  const float* b0   = (const float*)d_in[2];
  const float* W2   = (const float*)d_in[3];
  const float* b2   = (const float*)d_in[4];
  const float* W4   = (const float*)d_in[5];
  const float* b4   = (const float*)d_in[6];
  const float* W6   = (const float*)d_in[7];   // [256,64,4,4] = [256][1024]
  const float* b6   = (const float*)d_in[8];
  const float* Wr6  = (const float*)d_in[9];   // [16384,256]  (K,N)
  const float* br6  = (const float*)d_in[10];
  const float* W9   = (const float*)d_in[11];  // [2048,4096]  (N,K)
  const float* b9   = (const float*)d_in[12];
  const float* Wr9  = (const float*)d_in[13];  // [4096,2048]  (K,N)
  const float* br9  = (const float*)d_in[14];
  const float* W11  = (const float*)d_in[15];  // [2048,512]   (N,K)
  const float* b11  = (const float*)d_in[16];
  const float* Wr11 = (const float*)d_in[17];  // [512,2048]   (K,N)
  const float* br11 = (const float*)d_in[18];
  const float* W13  = (const float*)d_in[19];  // [40,512]
  const float* b13  = (const float*)d_in[20];
  const float* Wr13 = (const float*)d_in[21];  // [512,40]
  const float* br13 = (const float*)d_in[22];
  float* out = (float*)d_out;
  float* ws = (float*)d_ws;

  // Workspace (floats), 96 MB high-water mark (same as all prior rounds).
  float* R0  = ws;                           // 16,777,216 floats
  float* R1  = ws + 16777216;                //  4,194,304 floats
  float* y6  = ws + 16777216 + 4194304;      //  [1024,4096]
  // conv stage (chunk-local):
  float* y0c = R0;                           // [512,32,32,32] (full R0)
  float* y4c = R0;                           // [512,64,16,16] (y0 dead)
  float* c6c = R0 + 8388608;                 // [512,256,8,8]
  unsigned short* Wsp4 = (unsigned short*)(R0 + 10485760); // conv4 planes (y0 dead region)
  float* y2c = R1;                           // [512,32,16,16] (all of R1)
  float* s6  = R1;                           // [512,256] (y2 dead)
  float* p6  = R1 + 262144;                  // fp32 splitK partials 16*512*256
  unsigned short* Wsp = (unsigned short*)(R1 + 2359296);  // conv6 planes (y2 dead)
  // linear stage (R0 slots; conv buffers dead):
  float* l9  = R0;                           // [1024,2048]
  float* s9  = R0 + 2097152;                 // [1024,2048]
  float* y9  = R0 + 4194304;                 // [1024,512]
  float* l11 = R0 + 4718592;                 // [1024,2048]
  float* s11 = R0 + 6815744;                 // [1024,2048]
  float* y11 = R0 + 8912896;                 // [1024,512] ends 9,437,184
  float* p9  = R0 + 9437184;                 // scores9 partials 2*1024*2048

  for (int chunk = 0; chunk < 2; chunk++) {
    const int base = chunk * 512;
    k_conv0<<<512, 256, 0, stream>>>(x, W0, b0, y0c, base);
    k_conv2m<<<512, 256, 0, stream>>>(y0c, W2, b2, y2c);
    k_splitW4<<<72, 256, 0, stream>>>(W4, Wsp4);
    k_conv4m<<<512, 256, 0, stream>>>(y2c, Wsp4, b4, y4c);
    k_splitW<<<256, 256, 0, stream>>>(W6, Wsp);
    k_conv6m<<<512, 256, 0, stream>>>(y4c, Wsp, b6, c6c);
    dim3 g6(256 / 128, 512 / 64, 16);          // (2,8,16) = 256 blocks, 128 thr
    k_sgemm8<8, 0, 16><<<g6, 128, 0, stream>>>(y4c, Wr6, nullptr, p6, 512, 256, 16384);
    k_reduce6<<<512, 256, 0, stream>>>(p6, br6, s6, 512);
    k_topk<256, 64, 1><<<512, 256, 0, stream>>>(s6, c6c, y6 + (long)base * 4096);
  }

  dim3 g9m(16, 16, 1);
  // lin paths: MFMA (live-certified). Score paths: fp32 (bit-identical order).
  k_mgemm<1, 0, 1><<<g9m, 256, 0, stream>>>(y6, W9, b9, l9, 1024, 2048, 4096);
  dim3 gs9(2048 / 128, 1024 / 128, 2);         // (16,8,2) = 256 blocks, 256 thr
  k_sgemm8<16, 0, 2><<<gs9, 256, 0, stream>>>(y6, Wr9, nullptr, p9, 1024, 2048, 4096);
  k_reduce9<<<8192, 256, 0, stream>>>(p9, br9, s9);
  k_topk<2048, 512, 0><<<1024, 256, 0, stream>>>(s9, l9, y9);

  k_mgemm<1, 0, 1><<<g9m, 256, 0, stream>>>(y9, W11, b11, l11, 1024, 2048, 512);
  dim3 gs11(2048 / 64, 1024 / 64, 1);          // (32,16) = 512 blocks
  k_sgemm<0, 1, 1><<<gs11, 256, 0, stream>>>(y9, Wr11, br11, s11, 1024, 2048, 512);
  k_topk<2048, 512, 0><<<1024, 256, 0, stream>>>(s11, l11, y11);

  k_final<<<1024, 256, 0, stream>>>(y11, W13, b13, Wr13, br13, out);
}

// Round 14
// 1355.186 us; speedup vs baseline: 1.1959x; 1.1959x over previous
//
#include <hip/hip_runtime.h>
#include <stdint.h>

#define DEV __device__ __forceinline__

typedef __attribute__((ext_vector_type(8))) short bf16x8;
typedef __attribute__((ext_vector_type(8))) unsigned short u16x8;
typedef __attribute__((ext_vector_type(4))) float f32x4;

// RNE-round f to bf16 (top 16 bits), plus the rounded-away fp32 remainder.
DEV unsigned short rne1(float f, float& rem) {
  uint32_t u = __float_as_uint(f);
  uint32_t t = (u + 0x7fffu + ((u >> 16) & 1u)) & 0xffff0000u;
  rem = f - __uint_as_float(t);
  return (unsigned short)(t >> 16);
}
DEV void split3(float f, unsigned short& a0, unsigned short& a1, unsigned short& a2) {
  float r1, r2;
  a0 = rne1(f, r1);
  a1 = rne1(r1, r2);
  uint32_t u = __float_as_uint(r2);
  a2 = (unsigned short)((u + 0x7fffu + ((u >> 16) & 1u)) >> 16);
}
DEV void split3_4(float4 v, ushort4& h0, ushort4& h1, ushort4& h2) {
  split3(v.x, h0.x, h1.x, h2.x);
  split3(v.y, h0.y, h1.y, h2.y);
  split3(v.z, h0.z, h1.z, h2.z);
  split3(v.w, h0.w, h1.w, h2.w);
}

// ===== conv0 as MFMA split-3 implicit GEMM =============================
// grid (512 img, 4 quarters). Per block: C[32 oc][256 pix], K=27 pad 32.
// Weights split-3 staged to LDS (zero-padded); B-fragments built in-regs
// from fp32 padded image in LDS. Certified fragment/epilogue convention.
__global__ __launch_bounds__(256, 2) void k_conv0m(
    const float* __restrict__ x, const float* __restrict__ W,
    const float* __restrict__ b, float* __restrict__ y0, int base)
{
  __shared__ float sIn[3][34][34];                         // 13.9 KB
  __shared__ __align__(16) unsigned short sA[3][32][32];   // 6.1 KB
  const int t = threadIdx.x;
  const int lane = t & 63, wid = t >> 6;
  const int fr = lane & 15, kg = lane >> 4;
  const long img = base + blockIdx.x;
  const int q = blockIdx.y;
  const float mean[3] = {0.4914f, 0.4822f, 0.4465f};
  const float stdv[3] = {0.2023f, 0.1994f, 0.201f};
  for (int i = t; i < 3 * 34 * 34; i += 256) {
    int c = i / 1156, r = i % 1156, yy = r / 34 - 1, xx = r % 34 - 1;
    float v = 0.f;
    if ((unsigned)yy < 32u && (unsigned)xx < 32u)
      v = (x[((img * 3 + c) * 32 + yy) * 32 + xx] - mean[c]) / stdv[c];
    (&sIn[0][0][0])[i] = v;
  }
  for (int i = t; i < 32 * 32; i += 256) {
    const int oc = i >> 5, k = i & 31;
    float w = (k < 27) ? W[oc * 27 + k] : 0.f;
    unsigned short a0, a1, a2;
    split3(w, a0, a1, a2);
    sA[0][oc][k] = a0; sA[1][oc][k] = a1; sA[2][oc][k] = a2;
  }
  __syncthreads();

  f32x4 acc[2][4];
#pragma unroll
  for (int i = 0; i < 2; i++)
#pragma unroll
    for (int j = 0; j < 4; j++) acc[i][j] = (f32x4)0.f;

  bf16x8 bfv[3][4];
#pragma unroll
  for (int nf = 0; nf < 4; nf++) {
    const int pixel = q * 256 + wid * 64 + nf * 16 + fr;
    const int py = pixel >> 5, px = pixel & 31;
    bf16x8 h0, h1, h2;
#pragma unroll
    for (int j = 0; j < 8; j++) {
      const int k = kg * 8 + j;
      float v = 0.f;
      if (k < 27) {
        const int ic = k / 9, tap = k % 9;
        v = sIn[ic][py + tap / 3][px + tap % 3];
      }
      unsigned short a0, a1, a2;
      split3(v, a0, a1, a2);
      h0[j] = (short)a0; h1[j] = (short)a1; h2[j] = (short)a2;
    }
    bfv[0][nf] = h0; bfv[1][nf] = h1; bfv[2][nf] = h2;
  }

  bf16x8 af[3][2];
#pragma unroll
  for (int s = 0; s < 3; s++)
#pragma unroll
    for (int mf = 0; mf < 2; mf++)
      af[s][mf] = *(const bf16x8*)&sA[s][mf * 16 + fr][kg * 8];

#pragma unroll
  for (int mf = 0; mf < 2; mf++)
#pragma unroll
    for (int nf = 0; nf < 4; nf++) {
      f32x4 a = acc[mf][nf];
      a = __builtin_amdgcn_mfma_f32_16x16x32_bf16(af[1][mf], bfv[1][nf], a, 0, 0, 0);
      a = __builtin_amdgcn_mfma_f32_16x16x32_bf16(af[0][mf], bfv[2][nf], a, 0, 0, 0);
      a = __builtin_amdgcn_mfma_f32_16x16x32_bf16(af[2][mf], bfv[0][nf], a, 0, 0, 0);
      a = __builtin_amdgcn_mfma_f32_16x16x32_bf16(af[1][mf], bfv[0][nf], a, 0, 0, 0);
      a = __builtin_amdgcn_mfma_f32_16x16x32_bf16(af[0][mf], bfv[1][nf], a, 0, 0, 0);
      a = __builtin_amdgcn_mfma_f32_16x16x32_bf16(af[0][mf], bfv[0][nf], a, 0, 0, 0);
      acc[mf][nf] = a;
    }

#pragma unroll
  for (int mf = 0; mf < 2; mf++)
#pragma unroll
    for (int nf = 0; nf < 4; nf++) {
      const int pixBase = q * 256 + wid * 64 + nf * 16;
#pragma unroll
      for (int reg = 0; reg < 4; reg++) {
        const int oc = mf * 16 + kg * 4 + reg;
        y0[((long)blockIdx.x * 32 + oc) * 1024 + pixBase + fr] =
            fmaxf(acc[mf][nf][reg] + b[oc], 0.f);
      }
    }
}

// ===== conv2 as MFMA split-3 implicit GEMM (R12-proven) =================
__global__ __launch_bounds__(256, 2) void k_conv2m(
    const float* __restrict__ y0, const float* __restrict__ W2,
    const float* __restrict__ bb, float* __restrict__ y2)
{
  __shared__ __align__(16) unsigned short sB[3][256][40];   // 61.4 KB
  const int t = threadIdx.x;
  const int lane = t & 63, wid = t >> 6;
  const int fr = lane & 15, kg = lane >> 4;
  const long img = blockIdx.x;
  const int py = t >> 4, px = t & 15;
  const float* yimg = y0 + img * (32 * 1024);

  f32x4 acc[2][4];
#pragma unroll
  for (int i = 0; i < 2; i++)
#pragma unroll
    for (int j = 0; j < 4; j++) acc[i][j] = (f32x4)0.f;

#pragma unroll 1
  for (int ks = 0; ks < 16; ks++) {
    __syncthreads();
#pragma unroll
    for (int icL = 0; icL < 2; icL++) {
      const int ic = ks * 2 + icL;
#pragma unroll
      for (int ky = 0; ky < 4; ky++) {
        const int iy = 2 * py + ky - 1;
        float v[4];
#pragma unroll
        for (int kx = 0; kx < 4; kx++) {
          const int ix = 2 * px + kx - 1;
          v[kx] = ((unsigned)iy < 32u && (unsigned)ix < 32u)
                    ? yimg[(ic * 32 + iy) * 32 + ix] : 0.f;
        }
        ushort4 h0, h1, h2;
        split3_4(make_float4(v[0], v[1], v[2], v[3]), h0, h1, h2);
        const int kloc = icL * 16 + ky * 4;
        *(ushort4*)&sB[0][t][kloc] = h0;
        *(ushort4*)&sB[1][t][kloc] = h1;
        *(ushort4*)&sB[2][t][kloc] = h2;
      }
    }
    __syncthreads();

    bf16x8 bfv[3][4];
#pragma unroll
    for (int s = 0; s < 3; s++)
#pragma unroll
      for (int nf = 0; nf < 4; nf++)
        bfv[s][nf] = *(const bf16x8*)&sB[s][wid * 64 + nf * 16 + fr][kg * 8];

#pragma unroll
    for (int mf = 0; mf < 2; mf++) {
      const float* wr = W2 + (long)(mf * 16 + fr) * 512 + ks * 32 + kg * 8;
      float4 w0 = *(const float4*)wr;
      float4 w1 = *(const float4*)(wr + 4);
      ushort4 p0, p1, p2, q0, q1, q2;
      split3_4(w0, p0, p1, p2);
      split3_4(w1, q0, q1, q2);
      bf16x8 a0, a1, a2;
      a0[0]=(short)p0.x; a0[1]=(short)p0.y; a0[2]=(short)p0.z; a0[3]=(short)p0.w;
      a0[4]=(short)q0.x; a0[5]=(short)q0.y; a0[6]=(short)q0.z; a0[7]=(short)q0.w;
      a1[0]=(short)p1.x; a1[1]=(short)p1.y; a1[2]=(short)p1.z; a1[3]=(short)p1.w;
      a1[4]=(short)q1.x; a1[5]=(short)q1.y; a1[6]=(short)q1.z; a1[7]=(short)q1.w;
      a2[0]=(short)p2.x; a2[1]=(short)p2.y; a2[2]=(short)p2.z; a2[3]=(short)p2.w;
      a2[4]=(short)q2.x; a2[5]=(short)q2.y; a2[6]=(short)q2.z; a2[7]=(short)q2.w;
#pragma unroll
      for (int nf = 0; nf < 4; nf++) {
        f32x4 a = acc[mf][nf];
        a = __builtin_amdgcn_mfma_f32_16x16x32_bf16(a1, bfv[1][nf], a, 0, 0, 0);
        a = __builtin_amdgcn_mfma_f32_16x16x32_bf16(a0, bfv[2][nf], a, 0, 0, 0);
        a = __builtin_amdgcn_mfma_f32_16x16x32_bf16(a2, bfv[0][nf], a, 0, 0, 0);
        a = __builtin_amdgcn_mfma_f32_16x16x32_bf16(a1, bfv[0][nf], a, 0, 0, 0);
        a = __builtin_amdgcn_mfma_f32_16x16x32_bf16(a0, bfv[1][nf], a, 0, 0, 0);
        a = __builtin_amdgcn_mfma_f32_16x16x32_bf16(a0, bfv[0][nf], a, 0, 0, 0);
        acc[mf][nf] = a;
      }
    }
  }
#pragma unroll
  for (int mf = 0; mf < 2; mf++)
#pragma unroll
    for (int nf = 0; nf < 4; nf++) {
      const int pix = wid * 64 + nf * 16 + fr;
#pragma unroll
      for (int reg = 0; reg < 4; reg++) {
        const int oc = mf * 16 + kg * 4 + reg;
        y2[(img * 32 + oc) * 256 + pix] = fmaxf(acc[mf][nf][reg] + bb[oc], 0.f);
      }
    }
}

// ===== pre-split conv4 weights: W4 [64][32][3][3] -> [plane][tap][oc][ic] =
__global__ __launch_bounds__(256) void k_splitW4(
    const float* __restrict__ W, unsigned short* __restrict__ Wsp)
{
  const int i = blockIdx.x * 256 + threadIdx.x;   // 64*288 = 18432
  if (i >= 64 * 288) return;
  const int o = i / 288, r = i % 288, ic = r / 9, tap = r % 9;
  unsigned short a0, a1, a2;
  split3(W[i], a0, a1, a2);
  const int base = (tap * 64 + o) * 32 + ic;
  Wsp[base] = a0;
  Wsp[18432 + base] = a1;
  Wsp[36864 + base] = a2;
}

// ===== conv4 as MFMA split-3 implicit GEMM (R10-proven) =================
__global__ __launch_bounds__(256, 2) void k_conv4m(
    const float* __restrict__ y2, const unsigned short* __restrict__ Wsp,
    const float* __restrict__ bb, float* __restrict__ y4)
{
  __shared__ __align__(16) unsigned short sX[3][324][40];   // 77.8 KB
  const int t = threadIdx.x;
  const int lane = t & 63, wid = t >> 6;
  const int fr = lane & 15, kg = lane >> 4;
  const long img = blockIdx.x;
  const float* yimg = y2 + img * (32 * 256);

  for (int i = t; i < 324 * 32; i += 256) {
    const int ic = i / 324, pos = i % 324;
    const int iy = pos / 18, ix = pos % 18;
    float v = 0.f;
    if ((unsigned)(iy - 1) < 16u && (unsigned)(ix - 1) < 16u)
      v = yimg[(ic * 16 + iy - 1) * 16 + ix - 1];
    unsigned short a0, a1, a2;
    split3(v, a0, a1, a2);
    sX[0][pos][ic] = a0;
    sX[1][pos][ic] = a1;
    sX[2][pos][ic] = a2;
  }
  __syncthreads();

  f32x4 acc[4][4];
#pragma unroll
  for (int i = 0; i < 4; i++)
#pragma unroll
    for (int j = 0; j < 4; j++) acc[i][j] = (f32x4)0.f;

  const int pyb = wid * 4;
#pragma unroll 1
  for (int tap = 0; tap < 9; tap++) {
    const int ky = tap / 3, kx = tap % 3;
    bf16x8 bfv[3][4];
#pragma unroll
    for (int s = 0; s < 3; s++)
#pragma unroll
      for (int nf = 0; nf < 4; nf++)
        bfv[s][nf] = *(const bf16x8*)&sX[s][(pyb + nf + ky) * 18 + fr + kx][kg * 8];
#pragma unroll
    for (int mf = 0; mf < 4; mf++) {
      const int wb = (tap * 64 + mf * 16 + fr) * 32 + kg * 8;
      bf16x8 a0 = *(const bf16x8*)&Wsp[wb];
      bf16x8 a1 = *(const bf16x8*)&Wsp[18432 + wb];
      bf16x8 a2 = *(const bf16x8*)&Wsp[36864 + wb];
#pragma unroll
      for (int nf = 0; nf < 4; nf++) {
        f32x4 a = acc[mf][nf];
        a = __builtin_amdgcn_mfma_f32_16x16x32_bf16(a1, bfv[1][nf], a, 0, 0, 0);
        a = __builtin_amdgcn_mfma_f32_16x16x32_bf16(a0, bfv[2][nf], a, 0, 0, 0);
        a = __builtin_amdgcn_mfma_f32_16x16x32_bf16(a2, bfv[0][nf], a, 0, 0, 0);
        a = __builtin_amdgcn_mfma_f32_16x16x32_bf16(a1, bfv[0][nf], a, 0, 0, 0);
        a = __builtin_amdgcn_mfma_f32_16x16x32_bf16(a0, bfv[1][nf], a, 0, 0, 0);
        a = __builtin_amdgcn_mfma_f32_16x16x32_bf16(a0, bfv[0][nf], a, 0, 0, 0);
        acc[mf][nf] = a;
      }
    }
  }
#pragma unroll
  for (int mf = 0; mf < 4; mf++)
#pragma unroll
    for (int nf = 0; nf < 4; nf++) {
      const int p2 = wid * 64 + nf * 16 + fr;
#pragma unroll
      for (int reg = 0; reg < 4; reg++) {
        const int oc = mf * 16 + kg * 4 + reg;
        y4[(img * 64 + oc) * 256 + p2] = fmaxf(acc[mf][nf][reg] + bb[oc], 0.f);
      }
    }
}

// ===== pre-split conv6 weights: W6 [256][1024] fp32 -> 3 bf16 planes ====
__global__ __launch_bounds__(256) void k_splitW(
    const float* __restrict__ W, unsigned short* __restrict__ Wsp)
{
  const int i = (blockIdx.x * 256 + threadIdx.x) * 4;   // 262144 total
  float4 v = *(const float4*)&W[i];
  ushort4 h0, h1, h2; split3_4(v, h0, h1, h2);
  *(ushort4*)&Wsp[i]          = h0;
  *(ushort4*)&Wsp[262144 + i] = h1;
  *(ushort4*)&Wsp[524288 + i] = h2;
}

// ===== conv6 as MFMA split-3 implicit GEMM (R8-proven) ==================
__global__ __launch_bounds__(256) void k_conv6m(
    const float* __restrict__ y4, const unsigned short* __restrict__ Wsp,
    const float* __restrict__ bb, float* __restrict__ c6)
{
  __shared__ __align__(16) unsigned short sB[3][64][56];
  const int t = threadIdx.x;
  const int lane = t & 63, wid = t >> 6;
  const int fr = lane & 15, kg = lane >> 4;
  const long img = blockIdx.x;
  const int pix = t >> 2, q = t & 3;
  const int spy = pix >> 3, spx = pix & 7;
  const int icL = q >> 1, kyB = (q & 1) * 2;
  const float* yimg = y4 + img * (64 * 256);

  f32x4 acc[4][4];
#pragma unroll
  for (int i = 0; i < 4; i++)
#pragma unroll
    for (int j = 0; j < 4; j++) acc[i][j] = (f32x4)0.f;

#pragma unroll 1
  for (int ks = 0; ks < 32; ks++) {
    const int ic = ks * 2 + icL;
    float v[8];
#pragma unroll
    for (int j = 0; j < 8; j++) {
      const int ky = kyB + (j >> 2), kx = j & 3;
      const int iy = 2 * spy + ky - 1, ix = 2 * spx + kx - 1;
      v[j] = ((unsigned)iy < 16u && (unsigned)ix < 16u)
               ? yimg[(ic * 16 + iy) * 16 + ix] : 0.f;
    }
    u16x8 h0, h1, h2;
#pragma unroll
    for (int j = 0; j < 8; j++) {
      unsigned short a0, a1, a2;
      split3(v[j], a0, a1, a2);
      h0[j] = a0; h1[j] = a1; h2[j] = a2;
    }
    __syncthreads();
    *(u16x8*)&sB[0][pix][q * 8] = h0;
    *(u16x8*)&sB[1][pix][q * 8] = h1;
    *(u16x8*)&sB[2][pix][q * 8] = h2;
    __syncthreads();

    bf16x8 bfv[3][4];
#pragma unroll
    for (int s = 0; s < 3; s++)
#pragma unroll
      for (int nf = 0; nf < 4; nf++)
        bfv[s][nf] = *(const bf16x8*)&sB[s][nf * 16 + fr][kg * 8];

    const int kbase = ks * 32 + kg * 8;
#pragma unroll
    for (int mf = 0; mf < 4; mf++) {
      const int oc = wid * 64 + mf * 16 + fr;
      bf16x8 a0 = *(const bf16x8*)&Wsp[(long)oc * 1024 + kbase];
      bf16x8 a1 = *(const bf16x8*)&Wsp[(long)(256 + oc) * 1024 + kbase];
      bf16x8 a2 = *(const bf16x8*)&Wsp[(long)(512 + oc) * 1024 + kbase];
#pragma unroll
      for (int nf = 0; nf < 4; nf++) {
        f32x4 a = acc[mf][nf];
        a = __builtin_amdgcn_mfma_f32_16x16x32_bf16(a1, bfv[1][nf], a, 0, 0, 0);
        a = __builtin_amdgcn_mfma_f32_16x16x32_bf16(a0, bfv[2][nf], a, 0, 0, 0);
        a = __builtin_amdgcn_mfma_f32_16x16x32_bf16(a2, bfv[0][nf], a, 0, 0, 0);
        a = __builtin_amdgcn_mfma_f32_16x16x32_bf16(a1, bfv[0][nf], a, 0, 0, 0);
        a = __builtin_amdgcn_mfma_f32_16x16x32_bf16(a0, bfv[1][nf], a, 0, 0, 0);
        a = __builtin_amdgcn_mfma_f32_16x16x32_bf16(a0, bfv[0][nf], a, 0, 0, 0);
        acc[mf][nf] = a;
      }
    }
  }
#pragma unroll
  for (int mf = 0; mf < 4; mf++)
#pragma unroll
    for (int nf = 0; nf < 4; nf++) {
      const int ocb = wid * 64 + mf * 16 + kg * 4;
      const int p2 = nf * 16 + fr;
#pragma unroll
      for (int reg = 0; reg < 4; reg++) {
        const int oc = ocb + reg;
        c6[(img * 256 + oc) * 64 + p2] = acc[mf][nf][reg] + bb[oc];
      }
    }
}

// ====== fp32 score GEMM (R10/R12-proven 64x64, 4x4/thread, splitK) ======
template<int B_NK, int DO_ABS, int SPLITK>
__global__ __launch_bounds__(256, 4) void k_sgemm(
    const float* __restrict__ A, const float* __restrict__ Bm,
    const float* __restrict__ bias, float* __restrict__ C,
    int M, int N, int K)
{
  __shared__ float As[16][68];
  __shared__ float Bs[16][68];
  const int t = threadIdx.x;
  const int tx = t & 15, ty = t >> 4;
  const int n0 = blockIdx.x * 64, m0 = blockIdx.y * 64;
  const int Kc = K / SPLITK;
  const int k0 = blockIdx.z * Kc;
  float acc[4][4] = {{0.f}};
  for (int kt = 0; kt < Kc; kt += 16) {
    __syncthreads();
    {
      const int kc = t & 15, r0 = t >> 4;
#pragma unroll
      for (int i = 0; i < 4; i++)
        As[kc][r0 + 16 * i] = A[(long)(m0 + r0 + 16 * i) * K + k0 + kt + kc];
      if (B_NK) {
#pragma unroll
        for (int i = 0; i < 4; i++)
          Bs[kc][r0 + 16 * i] = Bm[(long)(n0 + r0 + 16 * i) * K + k0 + kt + kc];
      } else {
        const int nc = t & 63, kr0 = t >> 6;
#pragma unroll
        for (int i = 0; i < 4; i++)
          Bs[kr0 + 4 * i][nc] = Bm[(long)(k0 + kt + kr0 + 4 * i) * N + n0 + nc];
      }
    }
    __syncthreads();
    float part[4][4] = {{0.f}};
#pragma unroll
    for (int k = 0; k < 16; k++) {
      float4 av = *(const float4*)&As[k][ty * 4];
      float4 bv = *(const float4*)&Bs[k][tx * 4];
      const float a[4] = {av.x, av.y, av.z, av.w};
      const float bb[4] = {bv.x, bv.y, bv.z, bv.w};
#pragma unroll
      for (int i = 0; i < 4; i++)
#pragma unroll
        for (int j = 0; j < 4; j++)
          part[i][j] += a[i] * bb[j];
    }
#pragma unroll
    for (int i = 0; i < 4; i++)
#pragma unroll
      for (int j = 0; j < 4; j++)
        acc[i][j] += part[i][j];
  }
#pragma unroll
  for (int i = 0; i < 4; i++) {
    const long m = m0 + ty * 4 + i;
    float vv[4];
#pragma unroll
    for (int j = 0; j < 4; j++) {
      float u = acc[i][j];
      if (SPLITK == 1) {
        u += bias[n0 + tx * 4 + j];
        if (DO_ABS) u = fabsf(u);
      }
      vv[j] = u;
    }
    float4 v; v.x = vv[0]; v.y = vv[1]; v.z = vv[2]; v.w = vv[3];
    float* dst = (SPLITK == 1) ? &C[m * N + n0 + tx * 4]
                               : &C[((long)blockIdx.z * M + m) * N + n0 + tx * 4];
    *(float4*)dst = v;
  }
}

// ===== MFMA split-3 GEMM (live-certified B_NK=1; lin paths only) ========
template<int B_NK, int DO_ABS, int SPLITK>
__global__ __launch_bounds__(256, 2) void k_mgemm(
    const float* __restrict__ A, const float* __restrict__ Bm,
    const float* __restrict__ bias, float* __restrict__ C,
    int M, int N, int K)
{
  __shared__ __align__(16) unsigned short sA[3][64][40];
  __shared__ __align__(16) unsigned short sB[3][128][40];
  const int t = threadIdx.x;
  const int n0 = blockIdx.x * 128, m0 = blockIdx.y * 64;
  const int Kc = K / SPLITK;
  const int k0 = blockIdx.z * Kc;
  const int lane = t & 63, wid = t >> 6;
  const int wm = wid >> 1, wn = wid & 1;
  const int fr = lane & 15, kg = lane >> 4;

  f32x4 acc[2][4];
#pragma unroll
  for (int i = 0; i < 2; i++)
#pragma unroll
    for (int j = 0; j < 4; j++) acc[i][j] = (f32x4)0.f;

  for (int kt = 0; kt < Kc; kt += 32) {
    __syncthreads();
    {
      const int kq = t & 7, r = t >> 3;
#pragma unroll
      for (int i = 0; i < 2; i++) {
        float4 v = *(const float4*)&A[(long)(m0 + r + 32 * i) * K + k0 + kt + kq * 4];
        ushort4 h0, h1, h2; split3_4(v, h0, h1, h2);
        *(ushort4*)&sA[0][r + 32 * i][kq * 4] = h0;
        *(ushort4*)&sA[1][r + 32 * i][kq * 4] = h1;
        *(ushort4*)&sA[2][r + 32 * i][kq * 4] = h2;
      }
    }
    if (B_NK) {
      const int kq = t & 7, r = t >> 3;
#pragma unroll
      for (int i = 0; i < 4; i++) {
        float4 v = *(const float4*)&Bm[(long)(n0 + r + 32 * i) * K + k0 + kt + kq * 4];
        ushort4 h0, h1, h2; split3_4(v, h0, h1, h2);
        *(ushort4*)&sB[0][r + 32 * i][kq * 4] = h0;
        *(ushort4*)&sB[1][r + 32 * i][kq * 4] = h1;
        *(ushort4*)&sB[2][r + 32 * i][kq * 4] = h2;
      }
    } else {
      const int nq = t & 31, kr = t >> 5;
#pragma unroll
      for (int i = 0; i < 4; i++) {
        const int k = kr + 8 * i;
        float4 v = *(const float4*)&Bm[(long)(k0 + kt + k) * N + n0 + nq * 4];
        ushort4 h0, h1, h2; split3_4(v, h0, h1, h2);
        sB[0][nq * 4 + 0][k] = h0.x; sB[1][nq * 4 + 0][k] = h1.x; sB[2][nq * 4 + 0][k] = h2.x;
        sB[0][nq * 4 + 1][k] = h0.y; sB[1][nq * 4 + 1][k] = h1.y; sB[2][nq * 4 + 1][k] = h2.y;
        sB[0][nq * 4 + 2][k] = h0.z; sB[1][nq * 4 + 2][k] = h1.z; sB[2][nq * 4 + 2][k] = h2.z;
        sB[0][nq * 4 + 3][k] = h0.w; sB[1][nq * 4 + 3][k] = h1.w; sB[2][nq * 4 + 3][k] = h2.w;
      }
    }
    __syncthreads();

    bf16x8 af[3][2], bfv[3][4];
#pragma unroll
    for (int s = 0; s < 3; s++)
#pragma unroll
      for (int mf = 0; mf < 2; mf++)
        af[s][mf] = *(const bf16x8*)&sA[s][wm * 32 + mf * 16 + fr][kg * 8];
#pragma unroll
    for (int s = 0; s < 3; s++)
#pragma unroll
      for (int nf = 0; nf < 4; nf++)
        bfv[s][nf] = *(const bf16x8*)&sB[s][wn * 64 + nf * 16 + fr][kg * 8];

#pragma unroll
    for (int mf = 0; mf < 2; mf++)
#pragma unroll
      for (int nf = 0; nf < 4; nf++) {
        f32x4 a = acc[mf][nf];
        a = __builtin_amdgcn_mfma_f32_16x16x32_bf16(af[1][mf], bfv[1][nf], a, 0, 0, 0);
        a = __builtin_amdgcn_mfma_f32_16x16x32_bf16(af[0][mf], bfv[2][nf], a, 0, 0, 0);
        a = __builtin_amdgcn_mfma_f32_16x16x32_bf16(af[2][mf], bfv[0][nf], a, 0, 0, 0);
        a = __builtin_amdgcn_mfma_f32_16x16x32_bf16(af[1][mf], bfv[0][nf], a, 0, 0, 0);
        a = __builtin_amdgcn_mfma_f32_16x16x32_bf16(af[0][mf], bfv[1][nf], a, 0, 0, 0);
        a = __builtin_amdgcn_mfma_f32_16x16x32_bf16(af[0][mf], bfv[0][nf], a, 0, 0, 0);
        acc[mf][nf] = a;
      }
  }

  float* dst = (SPLITK == 1) ? C : C + (long)blockIdx.z * M * N;
#pragma unroll
  for (int mf = 0; mf < 2; mf++)
#pragma unroll
    for (int nf = 0; nf < 4; nf++) {
      const int n = n0 + wn * 64 + nf * 16 + fr;
      const int mb = m0 + wm * 32 + mf * 16 + kg * 4;
#pragma unroll
      for (int reg = 0; reg < 4; reg++) {
        float u = acc[mf][nf][reg];
        if (SPLITK == 1) {
          u += bias[n];
          if (DO_ABS) u = fabsf(u);
        }
        dst[(long)(mb + reg) * N + n] = u;
      }
    }
}

// ================= split-K reduce for scores6 (32 partials) ==============
__global__ __launch_bounds__(256) void k_reduce6(
    const float* __restrict__ part, const float* __restrict__ br,
    float* __restrict__ s6, int rows)
{
  const int i = blockIdx.x * 256 + threadIdx.x;
  const int tot = rows * 256;
  if (i < tot) {
    float s = br[i & 255];
#pragma unroll
    for (int z = 0; z < 32; z++) s += part[z * tot + i];
    s6[i] = fabsf(s);
  }
}

// ================= split-K reduce for scores9 (2 partials, N=2048) =======
__global__ __launch_bounds__(256) void k_reduce9(
    const float* __restrict__ part, const float* __restrict__ br,
    float* __restrict__ s9)
{
  const int i = blockIdx.x * 256 + threadIdx.x;   // 1024*2048 total
  const int tot = 1024 * 2048;
  s9[i] = fabsf(part[i] + part[tot + i] + br[i & 2047]);
}

// ================= block helpers =================
DEV int blk_reduce(int v, volatile int* sW4) {
#pragma unroll
  for (int d = 32; d > 0; d >>= 1) v += __shfl_down(v, d);
  const int lane = threadIdx.x & 63, wid = threadIdx.x >> 6;
  if (lane == 0) sW4[wid] = v;
  __syncthreads();
  int tot = sW4[0] + sW4[1] + sW4[2] + sW4[3];
  __syncthreads();
  return tot;
}

DEV int blk_exscan(int v, volatile int* sW4) {
  const int lane = threadIdx.x & 63, wid = threadIdx.x >> 6;
  int inc = v;
#pragma unroll
  for (int d = 1; d < 64; d <<= 1) {
    int u = __shfl_up(inc, d);
    if (lane >= d) inc += u;
  }
  if (lane == 63) sW4[wid] = inc;
  __syncthreads();
  int off = 0;
#pragma unroll
  for (int w = 0; w < 3; w++)
    if (w < wid) off += sW4[w];
  __syncthreads();
  return off + inc - v;
}

// ================= top-k select + gather (+relu) =================
template<int N, int KEEP, int SPATIAL>
__global__ __launch_bounds__(256) void k_topk(
    const float* __restrict__ scores, const float* __restrict__ full,
    float* __restrict__ out)
{
  constexpr int E = N / 256;
  __shared__ int sW4[4];
  __shared__ int sSel[KEEP];
  const int t = threadIdx.x;
  const long row = blockIdx.x;
  uint32_t kk[E];
#pragma unroll
  for (int e = 0; e < E; e++) kk[e] = __float_as_uint(scores[row * N + t * E + e]);
  uint32_t prefix = 0u;
  for (int bit = 31; bit >= 0; bit--) {
    uint32_t cand = prefix | (1u << bit);
    int c = 0;
#pragma unroll
    for (int e = 0; e < E; e++) c += (kk[e] >= cand) ? 1 : 0;
    if (blk_reduce(c, sW4) >= KEEP) prefix = cand;
  }
  int myG = 0, myE = 0;
#pragma unroll
  for (int e = 0; e < E; e++) { myG += kk[e] > prefix; myE += kk[e] == prefix; }
  const int G = blk_reduce(myG, sW4);
  const int needEq = KEEP - G;
  const int prefE = blk_exscan(myE, sW4);
  const int keepcnt = myG + max(0, min(myE, needEq - prefE));
  int pos = blk_exscan(keepcnt, sW4);
  int eqSeen = prefE;
#pragma unroll
  for (int e = 0; e < E; e++) {
    const bool kp = (kk[e] > prefix) || ((kk[e] == prefix) && (eqSeen < needEq));
    if (kk[e] == prefix) eqSeen++;
    if (kp) sSel[pos++] = t * E + e;
  }
  __syncthreads();
  if (SPATIAL) {
    for (int i = t; i < KEEP * 64; i += 256)
      out[row * (KEEP * 64) + i] = fmaxf(full[(row * N + sSel[i >> 6]) * 64 + (i & 63)], 0.f);
  } else {
    for (int i = t; i < KEEP; i += 256)
      out[row * KEEP + i] = fmaxf(full[row * N + sSel[i]], 0.f);
  }
}

// ================= final: lin13 + scores13 + top-10-of-40 =================
__global__ __launch_bounds__(256) void k_final(
    const float* __restrict__ y11, const float* __restrict__ W13,
    const float* __restrict__ b13, const float* __restrict__ Wr13,
    const float* __restrict__ br13, float* __restrict__ outp)
{
  __shared__ float sX[512];
  __shared__ float sL[64];
  __shared__ float sS[64];
  const int t = threadIdx.x;
  const long row = blockIdx.x;
  for (int i = t; i < 512; i += 256) sX[i] = y11[row * 512 + i];
  __syncthreads();
  if (t < 40) {
    float acc = b13[t];
    const float4* w4 = (const float4*)(W13 + t * 512);
    for (int k = 0; k < 128; k++) {
      float4 w = w4[k];
      acc += sX[4 * k] * w.x + sX[4 * k + 1] * w.y + sX[4 * k + 2] * w.z + sX[4 * k + 3] * w.w;
    }
    sL[t] = acc;
  } else if (t >= 64 && t < 104) {
    const int n = t - 64;
    float acc = br13[n];
    for (int k = 0; k < 512; k++) acc += sX[k] * Wr13[k * 40 + n];
    sS[n] = fabsf(acc);
  }
  __syncthreads();
  if (t < 64) {
    const uint32_t key = (t < 40) ? __float_as_uint(sS[t]) : 0u;
    uint32_t prefix = 0u;
#pragma unroll
    for (int bit = 31; bit >= 0; bit--) {
      uint32_t cand = prefix | (1u << bit);
      unsigned long long m = __ballot(t < 40 && key >= cand);
      if (__popcll(m) >= 10) prefix = cand;
    }
    const int G = __popcll(__ballot(t < 40 && key > prefix));
    const int needEq = 10 - G;
    const unsigned long long me = __ballot(t < 40 && key == prefix);
    const unsigned long long lt = (t == 0) ? 0ull : (~0ull >> (64 - t));
    const int eqr = __popcll(me & lt);
    const bool kp = (t < 40) && ((key > prefix) || (key == prefix && eqr < needEq));
    const int pos = __popcll(__ballot(kp) & lt);
    if (kp) outp[row * 10 + pos] = sL[t];
  }
}

// ================= launch =================
extern "C" void kernel_launch(void* const* d_in, const int* in_sizes, int n_in,
                              void* d_out, int out_size, void* d_ws, size_t ws_size,
                              hipStream_t stream)
{
  const float* x    = (const float*)d_in[0];
  const float* W0   = (const float*)d_in[1];
  const float* b0   = (const float*)d_in[2];
  const float* W2   = (const float*)d_in[3];
  const float* b2   = (const float*)d_in[4];
  const float* W4   = (const float*)d_in[5];
  const float* b4   = (const float*)d_in[6];
  const float* W6   = (const float*)d_in[7];   // [256,64,4,4] = [256][1024]
  const float* b6   = (const float*)d_in[8];
  const float* Wr6  = (const float*)d_in[9];   // [16384,256]  (K,N)
  const float* br6  = (const float*)d_in[10];
  const float* W9   = (const float*)d_in[11];  // [2048,4096]  (N,K)
  const float* b9   = (const float*)d_in[12];
  const float* Wr9  = (const float*)d_in[13];  // [4096,2048]  (K,N)
  const float* br9  = (const float*)d_in[14];
  const float* W11  = (const float*)d_in[15];  // [2048,512]   (N,K)
  const float* b11  = (const float*)d_in[16];
  const float* Wr11 = (const float*)d_in[17];  // [512,2048]   (K,N)
  const float* br11 = (const float*)d_in[18];
  const float* W13  = (const float*)d_in[19];  // [40,512]
  const float* b13  = (const float*)d_in[20];
  const float* Wr13 = (const float*)d_in[21];  // [512,40]
  const float* br13 = (const float*)d_in[22];
  float* out = (float*)d_out;
  float* ws = (float*)d_ws;

  // Workspace (floats), 96 MB high-water mark.
  float* R0  = ws;                           // 16,777,216 floats
  float* R1  = ws + 16777216;                //  4,194,304 floats
  float* y6  = ws + 16777216 + 4194304;      //  [1024,4096]
  // conv stage (chunk-local):
  float* y0c = R0;                           // [512,32,32,32] (full R0)
  float* y4c = R0;                           // [512,64,16,16] (y0 dead)
  float* c6c = R0 + 8388608;                 // [512,256,8,8]
  unsigned short* Wsp4 = (unsigned short*)(R0 + 10485760); // conv4 planes (pre-conv6m only)
  float* y2c = R1;                           // [512,32,16,16] (R1[0..2.1M))
  unsigned short* Wsp = (unsigned short*)(R1 + 2359296);  // conv6 planes (dead after conv6m)
  float* p6  = R1;                           // splitK partials 32*512*256 = all of R1
                                             // (written AFTER conv6m; y2c/Wsp dead)
  float* s6  = R0;                           // [512,256] (y4c region; dead after sgemm6)
  // linear stage (R0 slots; conv buffers dead):
  float* l9  = R0;                           // [1024,2048]
  float* s9  = R0 + 2097152;                 // [1024,2048]
  float* y9  = R0 + 4194304;                 // [1024,512]
  float* l11 = R0 + 4718592;                 // [1024,2048]
  float* s11 = R0 + 6815744;                 // [1024,2048]
  float* y11 = R0 + 8912896;                 // [1024,512] ends 9,437,184
  float* p9  = R0 + 9437184;                 // scores9 partials 2*1024*2048

  for (int chunk = 0; chunk < 2; chunk++) {
    const int base = chunk * 512;
    dim3 g0(512, 4);
    k_conv0m<<<g0, 256, 0, stream>>>(x, W0, b0, y0c, base);
    k_conv2m<<<512, 256, 0, stream>>>(y0c, W2, b2, y2c);
    k_splitW4<<<72, 256, 0, stream>>>(W4, Wsp4);
    k_conv4m<<<512, 256, 0, stream>>>(y2c, Wsp4, b4, y4c);
    k_splitW<<<256, 256, 0, stream>>>(W6, Wsp);
    k_conv6m<<<512, 256, 0, stream>>>(y4c, Wsp, b6, c6c);
    dim3 g6(256 / 64, 512 / 64, 32);           // (4,8,32) = 1024 blocks
    k_sgemm<0, 0, 32><<<g6, 256, 0, stream>>>(y4c, Wr6, nullptr, p6, 512, 256, 16384);
    k_reduce6<<<512, 256, 0, stream>>>(p6, br6, s6, 512);
    k_topk<256, 64, 1><<<512, 256, 0, stream>>>(s6, c6c, y6 + (long)base * 4096);
  }

  dim3 g9m(16, 16, 1);
  // lin paths: MFMA (live-certified). Score paths: fp32 (R12-proven kernel).
  k_mgemm<1, 0, 1><<<g9m, 256, 0, stream>>>(y6, W9, b9, l9, 1024, 2048, 4096);
  dim3 gs9(2048 / 64, 1024 / 64, 2);           // (32,16,2) = 1024 blocks
  k_sgemm<0, 0, 2><<<gs9, 256, 0, stream>>>(y6, Wr9, nullptr, p9, 1024, 2048, 4096);
  k_reduce9<<<8192, 256, 0, stream>>>(p9, br9, s9);
  k_topk<2048, 512, 0><<<1024, 256, 0, stream>>>(s9, l9, y9);

  k_mgemm<1, 0, 1><<<g9m, 256, 0, stream>>>(y9, W11, b11, l11, 1024, 2048, 512);
  dim3 gs11(2048 / 64, 1024 / 64, 1);          // (32,16) = 512 blocks
  k_sgemm<0, 1, 1><<<gs11, 256, 0, stream>>>(y9, Wr11, br11, s11, 1024, 2048, 512);
  k_topk<2048, 512, 0><<<1024, 256, 0, stream>>>(s11, l11, y11);

  k_final<<<1024, 256, 0, stream>>>(y11, W13, b13, Wr13, br13, out);
}

// Round 15
// 1342.875 us; speedup vs baseline: 1.2068x; 1.0092x over previous
//
#include <hip/hip_runtime.h>
#include <stdint.h>

#define DEV __device__ __forceinline__

typedef __attribute__((ext_vector_type(8))) short bf16x8;
typedef __attribute__((ext_vector_type(8))) unsigned short u16x8;
typedef __attribute__((ext_vector_type(4))) float f32x4;

// RNE-round f to bf16 (top 16 bits), plus the rounded-away fp32 remainder.
DEV unsigned short rne1(float f, float& rem) {
  uint32_t u = __float_as_uint(f);
  uint32_t t = (u + 0x7fffu + ((u >> 16) & 1u)) & 0xffff0000u;
  rem = f - __uint_as_float(t);
  return (unsigned short)(t >> 16);
}
DEV void split3(float f, unsigned short& a0, unsigned short& a1, unsigned short& a2) {
  float r1, r2;
  a0 = rne1(f, r1);
  a1 = rne1(r1, r2);
  uint32_t u = __float_as_uint(r2);
  a2 = (unsigned short)((u + 0x7fffu + ((u >> 16) & 1u)) >> 16);
}
DEV void split3_4(float4 v, ushort4& h0, ushort4& h1, ushort4& h2) {
  split3(v.x, h0.x, h1.x, h2.x);
  split3(v.y, h0.y, h1.y, h2.y);
  split3(v.z, h0.z, h1.z, h2.z);
  split3(v.w, h0.w, h1.w, h2.w);
}

// ===== conv0 as MFMA split-3 implicit GEMM (R14-proven) ================
__global__ __launch_bounds__(256, 2) void k_conv0m(
    const float* __restrict__ x, const float* __restrict__ W,
    const float* __restrict__ b, float* __restrict__ y0, int base)
{
  __shared__ float sIn[3][34][34];
  __shared__ __align__(16) unsigned short sA[3][32][32];
  const int t = threadIdx.x;
  const int lane = t & 63, wid = t >> 6;
  const int fr = lane & 15, kg = lane >> 4;
  const long img = base + blockIdx.x;
  const int q = blockIdx.y;
  const float mean[3] = {0.4914f, 0.4822f, 0.4465f};
  const float stdv[3] = {0.2023f, 0.1994f, 0.201f};
  for (int i = t; i < 3 * 34 * 34; i += 256) {
    int c = i / 1156, r = i % 1156, yy = r / 34 - 1, xx = r % 34 - 1;
    float v = 0.f;
    if ((unsigned)yy < 32u && (unsigned)xx < 32u)
      v = (x[((img * 3 + c) * 32 + yy) * 32 + xx] - mean[c]) / stdv[c];
    (&sIn[0][0][0])[i] = v;
  }
  for (int i = t; i < 32 * 32; i += 256) {
    const int oc = i >> 5, k = i & 31;
    float w = (k < 27) ? W[oc * 27 + k] : 0.f;
    unsigned short a0, a1, a2;
    split3(w, a0, a1, a2);
    sA[0][oc][k] = a0; sA[1][oc][k] = a1; sA[2][oc][k] = a2;
  }
  __syncthreads();

  f32x4 acc[2][4];
#pragma unroll
  for (int i = 0; i < 2; i++)
#pragma unroll
    for (int j = 0; j < 4; j++) acc[i][j] = (f32x4)0.f;

  bf16x8 bfv[3][4];
#pragma unroll
  for (int nf = 0; nf < 4; nf++) {
    const int pixel = q * 256 + wid * 64 + nf * 16 + fr;
    const int py = pixel >> 5, px = pixel & 31;
    bf16x8 h0, h1, h2;
#pragma unroll
    for (int j = 0; j < 8; j++) {
      const int k = kg * 8 + j;
      float v = 0.f;
      if (k < 27) {
        const int ic = k / 9, tap = k % 9;
        v = sIn[ic][py + tap / 3][px + tap % 3];
      }
      unsigned short a0, a1, a2;
      split3(v, a0, a1, a2);
      h0[j] = (short)a0; h1[j] = (short)a1; h2[j] = (short)a2;
    }
    bfv[0][nf] = h0; bfv[1][nf] = h1; bfv[2][nf] = h2;
  }

  bf16x8 af[3][2];
#pragma unroll
  for (int s = 0; s < 3; s++)
#pragma unroll
    for (int mf = 0; mf < 2; mf++)
      af[s][mf] = *(const bf16x8*)&sA[s][mf * 16 + fr][kg * 8];

#pragma unroll
  for (int mf = 0; mf < 2; mf++)
#pragma unroll
    for (int nf = 0; nf < 4; nf++) {
      f32x4 a = acc[mf][nf];
      a = __builtin_amdgcn_mfma_f32_16x16x32_bf16(af[1][mf], bfv[1][nf], a, 0, 0, 0);
      a = __builtin_amdgcn_mfma_f32_16x16x32_bf16(af[0][mf], bfv[2][nf], a, 0, 0, 0);
      a = __builtin_amdgcn_mfma_f32_16x16x32_bf16(af[2][mf], bfv[0][nf], a, 0, 0, 0);
      a = __builtin_amdgcn_mfma_f32_16x16x32_bf16(af[1][mf], bfv[0][nf], a, 0, 0, 0);
      a = __builtin_amdgcn_mfma_f32_16x16x32_bf16(af[0][mf], bfv[1][nf], a, 0, 0, 0);
      a = __builtin_amdgcn_mfma_f32_16x16x32_bf16(af[0][mf], bfv[0][nf], a, 0, 0, 0);
      acc[mf][nf] = a;
    }

#pragma unroll
  for (int mf = 0; mf < 2; mf++)
#pragma unroll
    for (int nf = 0; nf < 4; nf++) {
      const int pixBase = q * 256 + wid * 64 + nf * 16;
#pragma unroll
      for (int reg = 0; reg < 4; reg++) {
        const int oc = mf * 16 + kg * 4 + reg;
        y0[((long)blockIdx.x * 32 + oc) * 1024 + pixBase + fr] =
            fmaxf(acc[mf][nf][reg] + b[oc], 0.f);
      }
    }
}

// ===== conv2 as MFMA split-3 implicit GEMM (R12-proven) =================
__global__ __launch_bounds__(256, 2) void k_conv2m(
    const float* __restrict__ y0, const float* __restrict__ W2,
    const float* __restrict__ bb, float* __restrict__ y2)
{
  __shared__ __align__(16) unsigned short sB[3][256][40];
  const int t = threadIdx.x;
  const int lane = t & 63, wid = t >> 6;
  const int fr = lane & 15, kg = lane >> 4;
  const long img = blockIdx.x;
  const int py = t >> 4, px = t & 15;
  const float* yimg = y0 + img * (32 * 1024);

  f32x4 acc[2][4];
#pragma unroll
  for (int i = 0; i < 2; i++)
#pragma unroll
    for (int j = 0; j < 4; j++) acc[i][j] = (f32x4)0.f;

#pragma unroll 1
  for (int ks = 0; ks < 16; ks++) {
    __syncthreads();
#pragma unroll
    for (int icL = 0; icL < 2; icL++) {
      const int ic = ks * 2 + icL;
#pragma unroll
      for (int ky = 0; ky < 4; ky++) {
        const int iy = 2 * py + ky - 1;
        float v[4];
#pragma unroll
        for (int kx = 0; kx < 4; kx++) {
          const int ix = 2 * px + kx - 1;
          v[kx] = ((unsigned)iy < 32u && (unsigned)ix < 32u)
                    ? yimg[(ic * 32 + iy) * 32 + ix] : 0.f;
        }
        ushort4 h0, h1, h2;
        split3_4(make_float4(v[0], v[1], v[2], v[3]), h0, h1, h2);
        const int kloc = icL * 16 + ky * 4;
        *(ushort4*)&sB[0][t][kloc] = h0;
        *(ushort4*)&sB[1][t][kloc] = h1;
        *(ushort4*)&sB[2][t][kloc] = h2;
      }
    }
    __syncthreads();

    bf16x8 bfv[3][4];
#pragma unroll
    for (int s = 0; s < 3; s++)
#pragma unroll
      for (int nf = 0; nf < 4; nf++)
        bfv[s][nf] = *(const bf16x8*)&sB[s][wid * 64 + nf * 16 + fr][kg * 8];

#pragma unroll
    for (int mf = 0; mf < 2; mf++) {
      const float* wr = W2 + (long)(mf * 16 + fr) * 512 + ks * 32 + kg * 8;
      float4 w0 = *(const float4*)wr;
      float4 w1 = *(const float4*)(wr + 4);
      ushort4 p0, p1, p2, q0, q1, q2;
      split3_4(w0, p0, p1, p2);
      split3_4(w1, q0, q1, q2);
      bf16x8 a0, a1, a2;
      a0[0]=(short)p0.x; a0[1]=(short)p0.y; a0[2]=(short)p0.z; a0[3]=(short)p0.w;
      a0[4]=(short)q0.x; a0[5]=(short)q0.y; a0[6]=(short)q0.z; a0[7]=(short)q0.w;
      a1[0]=(short)p1.x; a1[1]=(short)p1.y; a1[2]=(short)p1.z; a1[3]=(short)p1.w;
      a1[4]=(short)q1.x; a1[5]=(short)q1.y; a1[6]=(short)q1.z; a1[7]=(short)q1.w;
      a2[0]=(short)p2.x; a2[1]=(short)p2.y; a2[2]=(short)p2.z; a2[3]=(short)p2.w;
      a2[4]=(short)q2.x; a2[5]=(short)q2.y; a2[6]=(short)q2.z; a2[7]=(short)q2.w;
#pragma unroll
      for (int nf = 0; nf < 4; nf++) {
        f32x4 a = acc[mf][nf];
        a = __builtin_amdgcn_mfma_f32_16x16x32_bf16(a1, bfv[1][nf], a, 0, 0, 0);
        a = __builtin_amdgcn_mfma_f32_16x16x32_bf16(a0, bfv[2][nf], a, 0, 0, 0);
        a = __builtin_amdgcn_mfma_f32_16x16x32_bf16(a2, bfv[0][nf], a, 0, 0, 0);
        a = __builtin_amdgcn_mfma_f32_16x16x32_bf16(a1, bfv[0][nf], a, 0, 0, 0);
        a = __builtin_amdgcn_mfma_f32_16x16x32_bf16(a0, bfv[1][nf], a, 0, 0, 0);
        a = __builtin_amdgcn_mfma_f32_16x16x32_bf16(a0, bfv[0][nf], a, 0, 0, 0);
        acc[mf][nf] = a;
      }
    }
  }
#pragma unroll
  for (int mf = 0; mf < 2; mf++)
#pragma unroll
    for (int nf = 0; nf < 4; nf++) {
      const int pix = wid * 64 + nf * 16 + fr;
#pragma unroll
      for (int reg = 0; reg < 4; reg++) {
        const int oc = mf * 16 + kg * 4 + reg;
        y2[(img * 32 + oc) * 256 + pix] = fmaxf(acc[mf][nf][reg] + bb[oc], 0.f);
      }
    }
}

// ===== pre-split conv4 weights: W4 [64][32][3][3] -> [plane][tap][oc][ic] =
__global__ __launch_bounds__(256) void k_splitW4(
    const float* __restrict__ W, unsigned short* __restrict__ Wsp)
{
  const int i = blockIdx.x * 256 + threadIdx.x;   // 64*288 = 18432
  if (i >= 64 * 288) return;
  const int o = i / 288, r = i % 288, ic = r / 9, tap = r % 9;
  unsigned short a0, a1, a2;
  split3(W[i], a0, a1, a2);
  const int base = (tap * 64 + o) * 32 + ic;
  Wsp[base] = a0;
  Wsp[18432 + base] = a1;
  Wsp[36864 + base] = a2;
}

// ===== conv4 as MFMA split-3 implicit GEMM (R10-proven) =================
__global__ __launch_bounds__(256, 2) void k_conv4m(
    const float* __restrict__ y2, const unsigned short* __restrict__ Wsp,
    const float* __restrict__ bb, float* __restrict__ y4)
{
  __shared__ __align__(16) unsigned short sX[3][324][40];
  const int t = threadIdx.x;
  const int lane = t & 63, wid = t >> 6;
  const int fr = lane & 15, kg = lane >> 4;
  const long img = blockIdx.x;
  const float* yimg = y2 + img * (32 * 256);

  for (int i = t; i < 324 * 32; i += 256) {
    const int ic = i / 324, pos = i % 324;
    const int iy = pos / 18, ix = pos % 18;
    float v = 0.f;
    if ((unsigned)(iy - 1) < 16u && (unsigned)(ix - 1) < 16u)
      v = yimg[(ic * 16 + iy - 1) * 16 + ix - 1];
    unsigned short a0, a1, a2;
    split3(v, a0, a1, a2);
    sX[0][pos][ic] = a0;
    sX[1][pos][ic] = a1;
    sX[2][pos][ic] = a2;
  }
  __syncthreads();

  f32x4 acc[4][4];
#pragma unroll
  for (int i = 0; i < 4; i++)
#pragma unroll
    for (int j = 0; j < 4; j++) acc[i][j] = (f32x4)0.f;

  const int pyb = wid * 4;
#pragma unroll 1
  for (int tap = 0; tap < 9; tap++) {
    const int ky = tap / 3, kx = tap % 3;
    bf16x8 bfv[3][4];
#pragma unroll
    for (int s = 0; s < 3; s++)
#pragma unroll
      for (int nf = 0; nf < 4; nf++)
        bfv[s][nf] = *(const bf16x8*)&sX[s][(pyb + nf + ky) * 18 + fr + kx][kg * 8];
#pragma unroll
    for (int mf = 0; mf < 4; mf++) {
      const int wb = (tap * 64 + mf * 16 + fr) * 32 + kg * 8;
      bf16x8 a0 = *(const bf16x8*)&Wsp[wb];
      bf16x8 a1 = *(const bf16x8*)&Wsp[18432 + wb];
      bf16x8 a2 = *(const bf16x8*)&Wsp[36864 + wb];
#pragma unroll
      for (int nf = 0; nf < 4; nf++) {
        f32x4 a = acc[mf][nf];
        a = __builtin_amdgcn_mfma_f32_16x16x32_bf16(a1, bfv[1][nf], a, 0, 0, 0);
        a = __builtin_amdgcn_mfma_f32_16x16x32_bf16(a0, bfv[2][nf], a, 0, 0, 0);
        a = __builtin_amdgcn_mfma_f32_16x16x32_bf16(a2, bfv[0][nf], a, 0, 0, 0);
        a = __builtin_amdgcn_mfma_f32_16x16x32_bf16(a1, bfv[0][nf], a, 0, 0, 0);
        a = __builtin_amdgcn_mfma_f32_16x16x32_bf16(a0, bfv[1][nf], a, 0, 0, 0);
        a = __builtin_amdgcn_mfma_f32_16x16x32_bf16(a0, bfv[0][nf], a, 0, 0, 0);
        acc[mf][nf] = a;
      }
    }
  }
#pragma unroll
  for (int mf = 0; mf < 4; mf++)
#pragma unroll
    for (int nf = 0; nf < 4; nf++) {
      const int p2 = wid * 64 + nf * 16 + fr;
#pragma unroll
      for (int reg = 0; reg < 4; reg++) {
        const int oc = mf * 16 + kg * 4 + reg;
        y4[(img * 64 + oc) * 256 + p2] = fmaxf(acc[mf][nf][reg] + bb[oc], 0.f);
      }
    }
}

// ===== pre-split conv6 weights: W6 [256][1024] fp32 -> 3 bf16 planes ====
__global__ __launch_bounds__(256) void k_splitW(
    const float* __restrict__ W, unsigned short* __restrict__ Wsp)
{
  const int i = (blockIdx.x * 256 + threadIdx.x) * 4;   // 262144 total
  float4 v = *(const float4*)&W[i];
  ushort4 h0, h1, h2; split3_4(v, h0, h1, h2);
  *(ushort4*)&Wsp[i]          = h0;
  *(ushort4*)&Wsp[262144 + i] = h1;
  *(ushort4*)&Wsp[524288 + i] = h2;
}

// ===== conv6 as MFMA split-3 implicit GEMM (R8-proven) ==================
__global__ __launch_bounds__(256) void k_conv6m(
    const float* __restrict__ y4, const unsigned short* __restrict__ Wsp,
    const float* __restrict__ bb, float* __restrict__ c6)
{
  __shared__ __align__(16) unsigned short sB[3][64][56];
  const int t = threadIdx.x;
  const int lane = t & 63, wid = t >> 6;
  const int fr = lane & 15, kg = lane >> 4;
  const long img = blockIdx.x;
  const int pix = t >> 2, q = t & 3;
  const int spy = pix >> 3, spx = pix & 7;
  const int icL = q >> 1, kyB = (q & 1) * 2;
  const float* yimg = y4 + img * (64 * 256);

  f32x4 acc[4][4];
#pragma unroll
  for (int i = 0; i < 4; i++)
#pragma unroll
    for (int j = 0; j < 4; j++) acc[i][j] = (f32x4)0.f;

#pragma unroll 1
  for (int ks = 0; ks < 32; ks++) {
    const int ic = ks * 2 + icL;
    float v[8];
#pragma unroll
    for (int j = 0; j < 8; j++) {
      const int ky = kyB + (j >> 2), kx = j & 3;
      const int iy = 2 * spy + ky - 1, ix = 2 * spx + kx - 1;
      v[j] = ((unsigned)iy < 16u && (unsigned)ix < 16u)
               ? yimg[(ic * 16 + iy) * 16 + ix] : 0.f;
    }
    u16x8 h0, h1, h2;
#pragma unroll
    for (int j = 0; j < 8; j++) {
      unsigned short a0, a1, a2;
      split3(v[j], a0, a1, a2);
      h0[j] = a0; h1[j] = a1; h2[j] = a2;
    }
    __syncthreads();
    *(u16x8*)&sB[0][pix][q * 8] = h0;
    *(u16x8*)&sB[1][pix][q * 8] = h1;
    *(u16x8*)&sB[2][pix][q * 8] = h2;
    __syncthreads();

    bf16x8 bfv[3][4];
#pragma unroll
    for (int s = 0; s < 3; s++)
#pragma unroll
      for (int nf = 0; nf < 4; nf++)
        bfv[s][nf] = *(const bf16x8*)&sB[s][nf * 16 + fr][kg * 8];

    const int kbase = ks * 32 + kg * 8;
#pragma unroll
    for (int mf = 0; mf < 4; mf++) {
      const int oc = wid * 64 + mf * 16 + fr;
      bf16x8 a0 = *(const bf16x8*)&Wsp[(long)oc * 1024 + kbase];
      bf16x8 a1 = *(const bf16x8*)&Wsp[(long)(256 + oc) * 1024 + kbase];
      bf16x8 a2 = *(const bf16x8*)&Wsp[(long)(512 + oc) * 1024 + kbase];
#pragma unroll
      for (int nf = 0; nf < 4; nf++) {
        f32x4 a = acc[mf][nf];
        a = __builtin_amdgcn_mfma_f32_16x16x32_bf16(a1, bfv[1][nf], a, 0, 0, 0);
        a = __builtin_amdgcn_mfma_f32_16x16x32_bf16(a0, bfv[2][nf], a, 0, 0, 0);
        a = __builtin_amdgcn_mfma_f32_16x16x32_bf16(a2, bfv[0][nf], a, 0, 0, 0);
        a = __builtin_amdgcn_mfma_f32_16x16x32_bf16(a1, bfv[0][nf], a, 0, 0, 0);
        a = __builtin_amdgcn_mfma_f32_16x16x32_bf16(a0, bfv[1][nf], a, 0, 0, 0);
        a = __builtin_amdgcn_mfma_f32_16x16x32_bf16(a0, bfv[0][nf], a, 0, 0, 0);
        acc[mf][nf] = a;
      }
    }
  }
#pragma unroll
  for (int mf = 0; mf < 4; mf++)
#pragma unroll
    for (int nf = 0; nf < 4; nf++) {
      const int ocb = wid * 64 + mf * 16 + kg * 4;
      const int p2 = nf * 16 + fr;
#pragma unroll
      for (int reg = 0; reg < 4; reg++) {
        const int oc = ocb + reg;
        c6[(img * 256 + oc) * 64 + p2] = acc[mf][nf][reg] + bb[oc];
      }
    }
}

// ====== fp32 score GEMM: 64x64, 4x4/thread, K-tile 32 (2 x 16-k blocks).
// Per-output FMA sequence BIT-IDENTICAL to the R10/R12/R14 kernel (same
// 16-k partial blocks in the same order) -> scores unchanged, zero flip
// risk. Half the barriers/staging overhead of the 16-k version.
template<int B_NK, int DO_ABS, int SPLITK>
__global__ __launch_bounds__(256, 4) void k_sgemm(
    const float* __restrict__ A, const float* __restrict__ Bm,
    const float* __restrict__ bias, float* __restrict__ C,
    int M, int N, int K)
{
  __shared__ float As[32][68];
  __shared__ float Bs[32][68];
  const int t = threadIdx.x;
  const int tx = t & 15, ty = t >> 4;
  const int n0 = blockIdx.x * 64, m0 = blockIdx.y * 64;
  const int Kc = K / SPLITK;
  const int k0 = blockIdx.z * Kc;
  float acc[4][4] = {{0.f}};
  for (int kt = 0; kt < Kc; kt += 32) {
    __syncthreads();
    {
      const int kc = t & 15, r0 = t >> 4;
#pragma unroll
      for (int h = 0; h < 2; h++)
#pragma unroll
        for (int i = 0; i < 4; i++)
          As[h * 16 + kc][r0 + 16 * i] =
              A[(long)(m0 + r0 + 16 * i) * K + k0 + kt + h * 16 + kc];
      if (B_NK) {
#pragma unroll
        for (int h = 0; h < 2; h++)
#pragma unroll
          for (int i = 0; i < 4; i++)
            Bs[h * 16 + kc][r0 + 16 * i] =
                Bm[(long)(n0 + r0 + 16 * i) * K + k0 + kt + h * 16 + kc];
      } else {
        const int nc = t & 63, kr0 = t >> 6;
#pragma unroll
        for (int h = 0; h < 2; h++)
#pragma unroll
          for (int i = 0; i < 4; i++)
            Bs[h * 16 + kr0 + 4 * i][nc] =
                Bm[(long)(k0 + kt + h * 16 + kr0 + 4 * i) * N + n0 + nc];
      }
    }
    __syncthreads();
#pragma unroll
    for (int h = 0; h < 2; h++) {
      float part[4][4] = {{0.f}};
#pragma unroll
      for (int k = 0; k < 16; k++) {
        float4 av = *(const float4*)&As[h * 16 + k][ty * 4];
        float4 bv = *(const float4*)&Bs[h * 16 + k][tx * 4];
        const float a[4] = {av.x, av.y, av.z, av.w};
        const float bb[4] = {bv.x, bv.y, bv.z, bv.w};
#pragma unroll
        for (int i = 0; i < 4; i++)
#pragma unroll
          for (int j = 0; j < 4; j++)
            part[i][j] += a[i] * bb[j];
      }
#pragma unroll
      for (int i = 0; i < 4; i++)
#pragma unroll
        for (int j = 0; j < 4; j++)
          acc[i][j] += part[i][j];
    }
  }
#pragma unroll
  for (int i = 0; i < 4; i++) {
    const long m = m0 + ty * 4 + i;
    float vv[4];
#pragma unroll
    for (int j = 0; j < 4; j++) {
      float u = acc[i][j];
      if (SPLITK == 1) {
        u += bias[n0 + tx * 4 + j];
        if (DO_ABS) u = fabsf(u);
      }
      vv[j] = u;
    }
    float4 v; v.x = vv[0]; v.y = vv[1]; v.z = vv[2]; v.w = vv[3];
    float* dst = (SPLITK == 1) ? &C[m * N + n0 + tx * 4]
                               : &C[((long)blockIdx.z * M + m) * N + n0 + tx * 4];
    *(float4*)dst = v;
  }
}

// ===== MFMA split-3 GEMM (live-certified B_NK=1; lin paths only) ========
template<int B_NK, int DO_ABS, int SPLITK>
__global__ __launch_bounds__(256, 2) void k_mgemm(
    const float* __restrict__ A, const float* __restrict__ Bm,
    const float* __restrict__ bias, float* __restrict__ C,
    int M, int N, int K)
{
  __shared__ __align__(16) unsigned short sA[3][64][40];
  __shared__ __align__(16) unsigned short sB[3][128][40];
  const int t = threadIdx.x;
  const int n0 = blockIdx.x * 128, m0 = blockIdx.y * 64;
  const int Kc = K / SPLITK;
  const int k0 = blockIdx.z * Kc;
  const int lane = t & 63, wid = t >> 6;
  const int wm = wid >> 1, wn = wid & 1;
  const int fr = lane & 15, kg = lane >> 4;

  f32x4 acc[2][4];
#pragma unroll
  for (int i = 0; i < 2; i++)
#pragma unroll
    for (int j = 0; j < 4; j++) acc[i][j] = (f32x4)0.f;

  for (int kt = 0; kt < Kc; kt += 32) {
    __syncthreads();
    {
      const int kq = t & 7, r = t >> 3;
#pragma unroll
      for (int i = 0; i < 2; i++) {
        float4 v = *(const float4*)&A[(long)(m0 + r + 32 * i) * K + k0 + kt + kq * 4];
        ushort4 h0, h1, h2; split3_4(v, h0, h1, h2);
        *(ushort4*)&sA[0][r + 32 * i][kq * 4] = h0;
        *(ushort4*)&sA[1][r + 32 * i][kq * 4] = h1;
        *(ushort4*)&sA[2][r + 32 * i][kq * 4] = h2;
      }
    }
    if (B_NK) {
      const int kq = t & 7, r = t >> 3;
#pragma unroll
      for (int i = 0; i < 4; i++) {
        float4 v = *(const float4*)&Bm[(long)(n0 + r + 32 * i) * K + k0 + kt + kq * 4];
        ushort4 h0, h1, h2; split3_4(v, h0, h1, h2);
        *(ushort4*)&sB[0][r + 32 * i][kq * 4] = h0;
        *(ushort4*)&sB[1][r + 32 * i][kq * 4] = h1;
        *(ushort4*)&sB[2][r + 32 * i][kq * 4] = h2;
      }
    } else {
      const int nq = t & 31, kr = t >> 5;
#pragma unroll
      for (int i = 0; i < 4; i++) {
        const int k = kr + 8 * i;
        float4 v = *(const float4*)&Bm[(long)(k0 + kt + k) * N + n0 + nq * 4];
        ushort4 h0, h1, h2; split3_4(v, h0, h1, h2);
        sB[0][nq * 4 + 0][k] = h0.x; sB[1][nq * 4 + 0][k] = h1.x; sB[2][nq * 4 + 0][k] = h2.x;
        sB[0][nq * 4 + 1][k] = h0.y; sB[1][nq * 4 + 1][k] = h1.y; sB[2][nq * 4 + 1][k] = h2.y;
        sB[0][nq * 4 + 2][k] = h0.z; sB[1][nq * 4 + 2][k] = h1.z; sB[2][nq * 4 + 2][k] = h2.z;
        sB[0][nq * 4 + 3][k] = h0.w; sB[1][nq * 4 + 3][k] = h1.w; sB[2][nq * 4 + 3][k] = h2.w;
      }
    }
    __syncthreads();

    bf16x8 af[3][2], bfv[3][4];
#pragma unroll
    for (int s = 0; s < 3; s++)
#pragma unroll
      for (int mf = 0; mf < 2; mf++)
        af[s][mf] = *(const bf16x8*)&sA[s][wm * 32 + mf * 16 + fr][kg * 8];
#pragma unroll
    for (int s = 0; s < 3; s++)
#pragma unroll
      for (int nf = 0; nf < 4; nf++)
        bfv[s][nf] = *(const bf16x8*)&sB[s][wn * 64 + nf * 16 + fr][kg * 8];

#pragma unroll
    for (int mf = 0; mf < 2; mf++)
#pragma unroll
      for (int nf = 0; nf < 4; nf++) {
        f32x4 a = acc[mf][nf];
        a = __builtin_amdgcn_mfma_f32_16x16x32_bf16(af[1][mf], bfv[1][nf], a, 0, 0, 0);
        a = __builtin_amdgcn_mfma_f32_16x16x32_bf16(af[0][mf], bfv[2][nf], a, 0, 0, 0);
        a = __builtin_amdgcn_mfma_f32_16x16x32_bf16(af[2][mf], bfv[0][nf], a, 0, 0, 0);
        a = __builtin_amdgcn_mfma_f32_16x16x32_bf16(af[1][mf], bfv[0][nf], a, 0, 0, 0);
        a = __builtin_amdgcn_mfma_f32_16x16x32_bf16(af[0][mf], bfv[1][nf], a, 0, 0, 0);
        a = __builtin_amdgcn_mfma_f32_16x16x32_bf16(af[0][mf], bfv[0][nf], a, 0, 0, 0);
        acc[mf][nf] = a;
      }
  }

  float* dst = (SPLITK == 1) ? C : C + (long)blockIdx.z * M * N;
#pragma unroll
  for (int mf = 0; mf < 2; mf++)
#pragma unroll
    for (int nf = 0; nf < 4; nf++) {
      const int n = n0 + wn * 64 + nf * 16 + fr;
      const int mb = m0 + wm * 32 + mf * 16 + kg * 4;
#pragma unroll
      for (int reg = 0; reg < 4; reg++) {
        float u = acc[mf][nf][reg];
        if (SPLITK == 1) {
          u += bias[n];
          if (DO_ABS) u = fabsf(u);
        }
        dst[(long)(mb + reg) * N + n] = u;
      }
    }
}

// ================= split-K reduce for scores6 (32 partials) ==============
__global__ __launch_bounds__(256) void k_reduce6(
    const float* __restrict__ part, const float* __restrict__ br,
    float* __restrict__ s6, int rows)
{
  const int i = blockIdx.x * 256 + threadIdx.x;
  const int tot = rows * 256;
  if (i < tot) {
    float s = br[i & 255];
#pragma unroll
    for (int z = 0; z < 32; z++) s += part[z * tot + i];
    s6[i] = fabsf(s);
  }
}

// ================= split-K reduce for scores9 (2 partials, N=2048) =======
__global__ __launch_bounds__(256) void k_reduce9(
    const float* __restrict__ part, const float* __restrict__ br,
    float* __restrict__ s9)
{
  const int i = blockIdx.x * 256 + threadIdx.x;   // 1024*2048 total
  const int tot = 1024 * 2048;
  s9[i] = fabsf(part[i] + part[tot + i] + br[i & 2047]);
}

// ================= block helpers =================
DEV int blk_reduce(int v, volatile int* sW4) {
#pragma unroll
  for (int d = 32; d > 0; d >>= 1) v += __shfl_down(v, d);
  const int lane = threadIdx.x & 63, wid = threadIdx.x >> 6;
  if (lane == 0) sW4[wid] = v;
  __syncthreads();
  int tot = sW4[0] + sW4[1] + sW4[2] + sW4[3];
  __syncthreads();
  return tot;
}

DEV int blk_exscan(int v, volatile int* sW4) {
  const int lane = threadIdx.x & 63, wid = threadIdx.x >> 6;
  int inc = v;
#pragma unroll
  for (int d = 1; d < 64; d <<= 1) {
    int u = __shfl_up(inc, d);
    if (lane >= d) inc += u;
  }
  if (lane == 63) sW4[wid] = inc;
  __syncthreads();
  int off = 0;
#pragma unroll
  for (int w = 0; w < 3; w++)
    if (w < wid) off += sW4[w];
  __syncthreads();
  return off + inc - v;
}

// ================= top-k select + gather (+relu) =================
template<int N, int KEEP, int SPATIAL>
__global__ __launch_bounds__(256) void k_topk(
    const float* __restrict__ scores, const float* __restrict__ full,
    float* __restrict__ out)
{
  constexpr int E = N / 256;
  __shared__ int sW4[4];
  __shared__ int sSel[KEEP];
  const int t = threadIdx.x;
  const long row = blockIdx.x;
  uint32_t kk[E];
#pragma unroll
  for (int e = 0; e < E; e++) kk[e] = __float_as_uint(scores[row * N + t * E + e]);
  uint32_t prefix = 0u;
  for (int bit = 31; bit >= 0; bit--) {
    uint32_t cand = prefix | (1u << bit);
    int c = 0;
#pragma unroll
    for (int e = 0; e < E; e++) c += (kk[e] >= cand) ? 1 : 0;
    if (blk_reduce(c, sW4) >= KEEP) prefix = cand;
  }
  int myG = 0, myE = 0;
#pragma unroll
  for (int e = 0; e < E; e++) { myG += kk[e] > prefix; myE += kk[e] == prefix; }
  const int G = blk_reduce(myG, sW4);
  const int needEq = KEEP - G;
  const int prefE = blk_exscan(myE, sW4);
  const int keepcnt = myG + max(0, min(myE, needEq - prefE));
  int pos = blk_exscan(keepcnt, sW4);
  int eqSeen = prefE;
#pragma unroll
  for (int e = 0; e < E; e++) {
    const bool kp = (kk[e] > prefix) || ((kk[e] == prefix) && (eqSeen < needEq));
    if (kk[e] == prefix) eqSeen++;
    if (kp) sSel[pos++] = t * E + e;
  }
  __syncthreads();
  if (SPATIAL) {
    for (int i = t; i < KEEP * 64; i += 256)
      out[row * (KEEP * 64) + i] = fmaxf(full[(row * N + sSel[i >> 6]) * 64 + (i & 63)], 0.f);
  } else {
    for (int i = t; i < KEEP; i += 256)
      out[row * KEEP + i] = fmaxf(full[row * N + sSel[i]], 0.f);
  }
}

// ================= final: lin13 + scores13 + top-10-of-40 =================
__global__ __launch_bounds__(256) void k_final(
    const float* __restrict__ y11, const float* __restrict__ W13,
    const float* __restrict__ b13, const float* __restrict__ Wr13,
    const float* __restrict__ br13, float* __restrict__ outp)
{
  __shared__ float sX[512];
  __shared__ float sL[64];
  __shared__ float sS[64];
  const int t = threadIdx.x;
  const long row = blockIdx.x;
  for (int i = t; i < 512; i += 256) sX[i] = y11[row * 512 + i];
  __syncthreads();
  if (t < 40) {
    float acc = b13[t];
    const float4* w4 = (const float4*)(W13 + t * 512);
    for (int k = 0; k < 128; k++) {
      float4 w = w4[k];
      acc += sX[4 * k] * w.x + sX[4 * k + 1] * w.y + sX[4 * k + 2] * w.z + sX[4 * k + 3] * w.w;
    }
    sL[t] = acc;
  } else if (t >= 64 && t < 104) {
    const int n = t - 64;
    float acc = br13[n];
    for (int k = 0; k < 512; k++) acc += sX[k] * Wr13[k * 40 + n];
    sS[n] = fabsf(acc);
  }
  __syncthreads();
  if (t < 64) {
    const uint32_t key = (t < 40) ? __float_as_uint(sS[t]) : 0u;
    uint32_t prefix = 0u;
#pragma unroll
    for (int bit = 31; bit >= 0; bit--) {
      uint32_t cand = prefix | (1u << bit);
      unsigned long long m = __ballot(t < 40 && key >= cand);
      if (__popcll(m) >= 10) prefix = cand;
    }
    const int G = __popcll(__ballot(t < 40 && key > prefix));
    const int needEq = 10 - G;
    const unsigned long long me = __ballot(t < 40 && key == prefix);
    const unsigned long long lt = (t == 0) ? 0ull : (~0ull >> (64 - t));
    const int eqr = __popcll(me & lt);
    const bool kp = (t < 40) && ((key > prefix) || (key == prefix && eqr < needEq));
    const int pos = __popcll(__ballot(kp) & lt);
    if (kp) outp[row * 10 + pos] = sL[t];
  }
}

// ================= launch =================
extern "C" void kernel_launch(void* const* d_in, const int* in_sizes, int n_in,
                              void* d_out, int out_size, void* d_ws, size_t ws_size,
                              hipStream_t stream)
{
  const float* x    = (const float*)d_in[0];
  const float* W0   = (const float*)d_in[1];
  const float* b0   = (const float*)d_in[2];
  const float* W2   = (const float*)d_in[3];
  const float* b2   = (const float*)d_in[4];
  const float* W4   = (const float*)d_in[5];
  const float* b4   = (const float*)d_in[6];
  const float* W6   = (const float*)d_in[7];   // [256,64,4,4] = [256][1024]
  const float* b6   = (const float*)d_in[8];
  const float* Wr6  = (const float*)d_in[9];   // [16384,256]  (K,N)
  const float* br6  = (const float*)d_in[10];
  const float* W9   = (const float*)d_in[11];  // [2048,4096]  (N,K)
  const float* b9   = (const float*)d_in[12];
  const float* Wr9  = (const float*)d_in[13];  // [4096,2048]  (K,N)
  const float* br9  = (const float*)d_in[14];
  const float* W11  = (const float*)d_in[15];  // [2048,512]   (N,K)
  const float* b11  = (const float*)d_in[16];
  const float* Wr11 = (const float*)d_in[17];  // [512,2048]   (K,N)
  const float* br11 = (const float*)d_in[18];
  const float* W13  = (const float*)d_in[19];  // [40,512]
  const float* b13  = (const float*)d_in[20];
  const float* Wr13 = (const float*)d_in[21];  // [512,40]
  const float* br13 = (const float*)d_in[22];
  float* out = (float*)d_out;
  float* ws = (float*)d_ws;

  // Workspace (floats), 96 MB high-water mark.
  float* R0  = ws;                           // 16,777,216 floats
  float* R1  = ws + 16777216;                //  4,194,304 floats
  float* y6  = ws + 16777216 + 4194304;      //  [1024,4096]
  // conv stage (chunk-local):
  float* y0c = R0;                           // [512,32,32,32] (full R0)
  float* y4c = R0;                           // [512,64,16,16] (y0 dead)
  float* c6c = R0 + 8388608;                 // [512,256,8,8]
  unsigned short* Wsp4 = (unsigned short*)(R0 + 10485760); // conv4 planes
  float* y2c = R1;                           // [512,32,16,16] (R1[0..2.1M))
  unsigned short* Wsp = (unsigned short*)(R1 + 2359296);  // conv6 planes
  float* p6  = R1;                           // splitK partials 32*512*256 (all R1; post-conv6m)
  float* s6  = R0;                           // [512,256] (y4c region; dead after sgemm6)
  // linear stage (R0 slots; conv buffers dead):
  float* l9  = R0;                           // [1024,2048]
  float* s9  = R0 + 2097152;                 // [1024,2048]
  float* y9  = R0 + 4194304;                 // [1024,512]
  float* l11 = R0 + 4718592;                 // [1024,2048]
  float* s11 = R0 + 6815744;                 // [1024,2048]
  float* y11 = R0 + 8912896;                 // [1024,512] ends 9,437,184
  float* p9  = R0 + 9437184;                 // scores9 partials 2*1024*2048

  for (int chunk = 0; chunk < 2; chunk++) {
    const int base = chunk * 512;
    dim3 g0(512, 4);
    k_conv0m<<<g0, 256, 0, stream>>>(x, W0, b0, y0c, base);
    k_conv2m<<<512, 256, 0, stream>>>(y0c, W2, b2, y2c);
    k_splitW4<<<72, 256, 0, stream>>>(W4, Wsp4);
    k_conv4m<<<512, 256, 0, stream>>>(y2c, Wsp4, b4, y4c);
    k_splitW<<<256, 256, 0, stream>>>(W6, Wsp);
    k_conv6m<<<512, 256, 0, stream>>>(y4c, Wsp, b6, c6c);
    dim3 g6(256 / 64, 512 / 64, 32);           // (4,8,32) = 1024 blocks
    k_sgemm<0, 0, 32><<<g6, 256, 0, stream>>>(y4c, Wr6, nullptr, p6, 512, 256, 16384);
    k_reduce6<<<512, 256, 0, stream>>>(p6, br6, s6, 512);
    k_topk<256, 64, 1><<<512, 256, 0, stream>>>(s6, c6c, y6 + (long)base * 4096);
  }

  dim3 g9m(16, 16, 1);
  // lin paths: MFMA (live-certified). Score paths: fp32 (bit-identical order).
  k_mgemm<1, 0, 1><<<g9m, 256, 0, stream>>>(y6, W9, b9, l9, 1024, 2048, 4096);
  dim3 gs9(2048 / 64, 1024 / 64, 2);           // (32,16,2) = 1024 blocks
  k_sgemm<0, 0, 2><<<gs9, 256, 0, stream>>>(y6, Wr9, nullptr, p9, 1024, 2048, 4096);
  k_reduce9<<<8192, 256, 0, stream>>>(p9, br9, s9);
  k_topk<2048, 512, 0><<<1024, 256, 0, stream>>>(s9, l9, y9);

  k_mgemm<1, 0, 1><<<g9m, 256, 0, stream>>>(y9, W11, b11, l11, 1024, 2048, 512);
  dim3 gs11(2048 / 64, 1024 / 64, 1);          // (32,16) = 512 blocks
  k_sgemm<0, 1, 1><<<gs11, 256, 0, stream>>>(y9, Wr11, br11, s11, 1024, 2048, 512);
  k_topk<2048, 512, 0><<<1024, 256, 0, stream>>>(s11, l11, y11);

  k_final<<<1024, 256, 0, stream>>>(y11, W13, b13, Wr13, br13, out);
}